// Round 1
// baseline (1754.010 us; speedup 1.0000x reference)
//
#include <hip/hip_runtime.h>
#include <math.h>

#define HID 32
#define TDIM 128
#define NNODE 100000
#define NEDGE 800000
#define NGRAPH 512

__device__ __forceinline__ float silu_f(float v) { return v / (1.0f + __expf(-v)); }
__device__ __forceinline__ float sigmoid_f(float v) { return 1.0f / (1.0f + __expf(-v)); }

// ---------------- K1: time MLP  ss = silu(time@W1+b1)@W2+b2  (G x 64) ----------------
__global__ void time_mlp_kernel(const float* __restrict__ timein,
                                const float* __restrict__ w1, const float* __restrict__ b1,
                                const float* __restrict__ w2, const float* __restrict__ b2,
                                float* __restrict__ ss) {
    __shared__ float t[TDIM];
    __shared__ float h[2 * HID];
    const int g = blockIdx.x;
    const int c = threadIdx.x;  // 0..63
    t[c]      = timein[g * TDIM + c];
    t[64 + c] = timein[g * TDIM + 64 + c];
    __syncthreads();
    float acc = b1[c];
#pragma unroll
    for (int k = 0; k < TDIM; ++k) acc = fmaf(t[k], w1[k * 2 * HID + c], acc);
    h[c] = silu_f(acc);
    __syncthreads();
    float acc2 = b2[c];
#pragma unroll
    for (int k = 0; k < 2 * HID; ++k) acc2 = fmaf(h[k], w2[k * 2 * HID + c], acc2);
    ss[g * 2 * HID + c] = acc2;
}

// ---------------- K2: node pre-transform + zero accumulators ----------------
__global__ void node_pre_kernel(const float* __restrict__ x, const int* __restrict__ batch,
                                const float* __restrict__ ss,
                                float* __restrict__ x_t, float* __restrict__ m_i,
                                float* __restrict__ sum_p, float* __restrict__ cnt) {
    const int tid = blockIdx.x * blockDim.x + threadIdx.x;  // exactly N*32 threads
    const int n = tid >> 5, c = tid & 31;
    const int g = batch[n];
    const float scale = ss[g * 64 + c];
    const float shift = ss[g * 64 + 32 + c];
    const float v = x[tid];
    x_t[tid] = silu_f(fmaf(v, scale, v) + shift);  // v*(1+scale)+shift
    m_i[tid] = 0.0f;
    if (c < 3) sum_p[n * 3 + c] = 0.0f;
    if (c == 0) cnt[n] = 0.0f;
}

// ---------------- K3: edge kernel (thread per edge) ----------------
__global__ __launch_bounds__(256) void edge_kernel(
    const int* __restrict__ ei, const float* __restrict__ x_t, const float* __restrict__ pos,
    const float* __restrict__ rbf_means, const float* __restrict__ rbf_betas,
    const float* __restrict__ w_dist,
    const float* __restrict__ msg_w1, const float* __restrict__ msg_b1,
    const float* __restrict__ msg_w2, const float* __restrict__ msg_b2,
    const float* __restrict__ gate_w, const float* __restrict__ gate_b,
    const float* __restrict__ coord_w1, const float* __restrict__ coord_b1,
    const float* __restrict__ coord_w2, const float* __restrict__ coord_b2,
    float* __restrict__ m_i, float* __restrict__ sum_p, float* __restrict__ cnt) {
    const int e = blockIdx.x * blockDim.x + threadIdx.x;
    if (e >= NEDGE) return;
    const int i = ei[e];
    const int j = ei[NEDGE + e];

    float xi[HID], xj[HID];
    {
        const float4* a4 = (const float4*)(x_t + i * HID);
        const float4* b4 = (const float4*)(x_t + j * HID);
#pragma unroll
        for (int q = 0; q < HID / 4; ++q) {
            float4 a = a4[q];
            xi[q * 4 + 0] = a.x; xi[q * 4 + 1] = a.y; xi[q * 4 + 2] = a.z; xi[q * 4 + 3] = a.w;
            float4 b = b4[q];
            xj[q * 4 + 0] = b.x; xj[q * 4 + 1] = b.y; xj[q * 4 + 2] = b.z; xj[q * 4 + 3] = b.w;
        }
    }

    // h = silu(cat(xi,xj) @ msg_w1 + b1)
    float h[HID];
#pragma unroll
    for (int c = 0; c < HID; ++c) h[c] = msg_b1[c];
#pragma unroll
    for (int k = 0; k < HID; ++k) {
        const float a = xi[k], b = xj[k];
#pragma unroll
        for (int c = 0; c < HID; ++c) {
            h[c] = fmaf(a, msg_w1[k * HID + c], h[c]);
            h[c] = fmaf(b, msg_w1[(HID + k) * HID + c], h[c]);
        }
    }
#pragma unroll
    for (int c = 0; c < HID; ++c) h[c] = silu_f(h[c]);

    // m = silu(h @ msg_w2 + b2)
    float m[HID];
#pragma unroll
    for (int c = 0; c < HID; ++c) m[c] = msg_b2[c];
#pragma unroll
    for (int k = 0; k < HID; ++k) {
        const float a = h[k];
#pragma unroll
        for (int c = 0; c < HID; ++c) m[c] = fmaf(a, msg_w2[k * HID + c], m[c]);
    }
#pragma unroll
    for (int c = 0; c < HID; ++c) m[c] = silu_f(m[c]);

    // gate = sigmoid(xj @ gate_w + gate_b); m *= gate
    {
        float ga[HID];
#pragma unroll
        for (int c = 0; c < HID; ++c) ga[c] = gate_b[c];
#pragma unroll
        for (int k = 0; k < HID; ++k) {
            const float a = xj[k];
#pragma unroll
            for (int c = 0; c < HID; ++c) ga[c] = fmaf(a, gate_w[k * HID + c], ga[c]);
        }
#pragma unroll
        for (int c = 0; c < HID; ++c) m[c] *= sigmoid_f(ga[c]);
    }

    // geometry: dist, cutoff, rbf, dist_emb; m *= cutoff * (rbf @ w_dist)
    const float p0 = pos[i * 3 + 0] - pos[j * 3 + 0];
    const float p1 = pos[i * 3 + 1] - pos[j * 3 + 1];
    const float p2 = pos[i * 3 + 2] - pos[j * 3 + 2];
    const float dist = sqrtf(p0 * p0 + p1 * p1 + p2 * p2);
    const float dcl = fminf(dist, 5.0f);
    const float cutoff = 0.5f * (__cosf(dcl * 0.6283185307179586f) + 1.0f);  // pi/5
    const float edm = __expf(-dist);
    {
        float rbf[HID];
#pragma unroll
        for (int c = 0; c < HID; ++c) {
            const float t = edm - rbf_means[c];
            rbf[c] = __expf(-rbf_betas[c] * t * t);
        }
        float de[HID];
#pragma unroll
        for (int c = 0; c < HID; ++c) de[c] = 0.0f;
#pragma unroll
        for (int k = 0; k < HID; ++k) {
            const float a = rbf[k];
#pragma unroll
            for (int c = 0; c < HID; ++c) de[c] = fmaf(a, w_dist[k * HID + c], de[c]);
        }
#pragma unroll
        for (int c = 0; c < HID; ++c) m[c] *= cutoff * de[c];
    }

    // scatter m into m_i[j]
    {
        float* dst = m_i + j * HID;
#pragma unroll
        for (int c = 0; c < HID; ++c) unsafeAtomicAdd(dst + c, m[c]);
    }

    // s = silu(m @ coord_w1 + cb1) @ coord_w2 + cb2   (scalar)
    float s;
    {
        float sa[HID];
#pragma unroll
        for (int c = 0; c < HID; ++c) sa[c] = coord_b1[c];
#pragma unroll
        for (int k = 0; k < HID; ++k) {
            const float a = m[k];
#pragma unroll
            for (int c = 0; c < HID; ++c) sa[c] = fmaf(a, coord_w1[k * HID + c], sa[c]);
        }
        s = coord_b2[0];
#pragma unroll
        for (int c = 0; c < HID; ++c) s = fmaf(silu_f(sa[c]), coord_w2[c], s);
    }

    unsafeAtomicAdd(&sum_p[j * 3 + 0], p0 * s);
    unsafeAtomicAdd(&sum_p[j * 3 + 1], p1 * s);
    unsafeAtomicAdd(&sum_p[j * 3 + 2], p2 * s);
    unsafeAtomicAdd(&cnt[j], 1.0f);
}

// ---------------- K4: node post (comb MLP + pos update) ----------------
__global__ void node_post_kernel(const float* __restrict__ x_t, const float* __restrict__ m_i,
                                 const float* __restrict__ pos, const float* __restrict__ sum_p,
                                 const float* __restrict__ cnt,
                                 const float* __restrict__ comb_w1, const float* __restrict__ comb_b1,
                                 const float* __restrict__ comb_w2, const float* __restrict__ comb_b2,
                                 float* __restrict__ out_x, float* __restrict__ out_pos) {
    const int n = blockIdx.x * blockDim.x + threadIdx.x;
    if (n >= NNODE) return;
    float xt[HID], mi[HID];
    {
        const float4* a4 = (const float4*)(x_t + n * HID);
        const float4* b4 = (const float4*)(m_i + n * HID);
#pragma unroll
        for (int q = 0; q < HID / 4; ++q) {
            float4 a = a4[q];
            xt[q * 4 + 0] = a.x; xt[q * 4 + 1] = a.y; xt[q * 4 + 2] = a.z; xt[q * 4 + 3] = a.w;
            float4 b = b4[q];
            mi[q * 4 + 0] = b.x; mi[q * 4 + 1] = b.y; mi[q * 4 + 2] = b.z; mi[q * 4 + 3] = b.w;
        }
    }
    float h[HID];
#pragma unroll
    for (int c = 0; c < HID; ++c) h[c] = comb_b1[c];
#pragma unroll
    for (int k = 0; k < HID; ++k) {
        const float a = xt[k], b = mi[k];
#pragma unroll
        for (int c = 0; c < HID; ++c) {
            h[c] = fmaf(a, comb_w1[k * HID + c], h[c]);
            h[c] = fmaf(b, comb_w1[(HID + k) * HID + c], h[c]);
        }
    }
#pragma unroll
    for (int c = 0; c < HID; ++c) h[c] = silu_f(h[c]);
    float c2[HID];
#pragma unroll
    for (int c = 0; c < HID; ++c) c2[c] = comb_b2[c];
#pragma unroll
    for (int k = 0; k < HID; ++k) {
        const float a = h[k];
#pragma unroll
        for (int c = 0; c < HID; ++c) c2[c] = fmaf(a, comb_w2[k * HID + c], c2[c]);
    }
#pragma unroll
    for (int c = 0; c < HID; ++c) out_x[n * HID + c] = silu_f(xt[c] + c2[c]);

    const float inv = 1.0f / fmaxf(cnt[n], 1.0f);
#pragma unroll
    for (int d = 0; d < 3; ++d) out_pos[n * 3 + d] = fmaf(sum_p[n * 3 + d], inv, pos[n * 3 + d]);
}

// ---------------- launch ----------------
extern "C" void kernel_launch(void* const* d_in, const int* in_sizes, int n_in,
                              void* d_out, int out_size, void* d_ws, size_t ws_size,
                              hipStream_t stream) {
    const float* x        = (const float*)d_in[0];
    const int*   ei       = (const int*)d_in[1];
    const float* pos      = (const float*)d_in[2];
    const float* timein   = (const float*)d_in[3];
    const int*   batch    = (const int*)d_in[4];
    const float* rbfm     = (const float*)d_in[5];
    const float* rbfb     = (const float*)d_in[6];
    const float* w_dist   = (const float*)d_in[7];
    const float* msg_w1   = (const float*)d_in[8];
    const float* msg_b1   = (const float*)d_in[9];
    const float* msg_w2   = (const float*)d_in[10];
    const float* msg_b2   = (const float*)d_in[11];
    const float* gate_w   = (const float*)d_in[12];
    const float* gate_b   = (const float*)d_in[13];
    const float* time_w1  = (const float*)d_in[14];
    const float* time_b1  = (const float*)d_in[15];
    const float* time_w2  = (const float*)d_in[16];
    const float* time_b2  = (const float*)d_in[17];
    const float* comb_w1  = (const float*)d_in[18];
    const float* comb_b1  = (const float*)d_in[19];
    const float* comb_w2  = (const float*)d_in[20];
    const float* comb_b2  = (const float*)d_in[21];
    const float* coord_w1 = (const float*)d_in[22];
    const float* coord_b1 = (const float*)d_in[23];
    const float* coord_w2 = (const float*)d_in[24];
    const float* coord_b2 = (const float*)d_in[25];

    float* ws    = (float*)d_ws;
    float* ss    = ws;                       // G*64         = 32768
    float* x_t   = ss + NGRAPH * 64;         // N*32         = 3.2M
    float* m_i   = x_t + NNODE * HID;        // N*32         = 3.2M
    float* sum_p = m_i + NNODE * HID;        // N*3
    float* cnt   = sum_p + NNODE * 3;        // N

    float* out_x   = (float*)d_out;          // N*32
    float* out_pos = out_x + NNODE * HID;    // N*3

    time_mlp_kernel<<<NGRAPH, 64, 0, stream>>>(timein, time_w1, time_b1, time_w2, time_b2, ss);
    node_pre_kernel<<<(NNODE * HID) / 256, 256, 0, stream>>>(x, batch, ss, x_t, m_i, sum_p, cnt);
    edge_kernel<<<(NEDGE + 255) / 256, 256, 0, stream>>>(ei, x_t, pos, rbfm, rbfb, w_dist,
                                                         msg_w1, msg_b1, msg_w2, msg_b2,
                                                         gate_w, gate_b, coord_w1, coord_b1,
                                                         coord_w2, coord_b2, m_i, sum_p, cnt);
    node_post_kernel<<<(NNODE + 255) / 256, 256, 0, stream>>>(x_t, m_i, pos, sum_p, cnt,
                                                              comb_w1, comb_b1, comb_w2, comb_b2,
                                                              out_x, out_pos);
}

// Round 2
// 627.673 us; speedup vs baseline: 2.7945x; 2.7945x over previous
//
#include <hip/hip_runtime.h>
#include <math.h>

#define HID 32
#define TDIM 128
#define NNODE 100000
#define NEDGE 800000
#define NGRAPH 512
#define SCAN_BLK 1024
#define NBLK1 ((NNODE + SCAN_BLK - 1) / SCAN_BLK)   // 98

__device__ __forceinline__ float silu_f(float v) { return v / (1.0f + __expf(-v)); }
__device__ __forceinline__ float sigmoid_f(float v) { return 1.0f / (1.0f + __expf(-v)); }
__device__ __forceinline__ unsigned int bf16r(float f) {
    unsigned int u = __float_as_uint(f);
    return (u + 0x7FFFu + ((u >> 16) & 1u)) >> 16;   // round-to-nearest-even bf16
}
__device__ __forceinline__ float bf16tof(unsigned short h) {
    return __uint_as_float(((unsigned int)h) << 16);
}

// ---------------- K1: time MLP  ss = silu(time@W1+b1)@W2+b2  (G x 64) ----------------
__global__ void time_mlp_kernel(const float* __restrict__ timein,
                                const float* __restrict__ w1, const float* __restrict__ b1,
                                const float* __restrict__ w2, const float* __restrict__ b2,
                                float* __restrict__ ss) {
    __shared__ float t[TDIM];
    __shared__ float h[2 * HID];
    const int g = blockIdx.x;
    const int c = threadIdx.x;  // 0..63
    t[c]      = timein[g * TDIM + c];
    t[64 + c] = timein[g * TDIM + 64 + c];
    __syncthreads();
    float acc = b1[c];
#pragma unroll
    for (int k = 0; k < TDIM; ++k) acc = fmaf(t[k], w1[k * 2 * HID + c], acc);
    h[c] = silu_f(acc);
    __syncthreads();
    float acc2 = b2[c];
#pragma unroll
    for (int k = 0; k < 2 * HID; ++k) acc2 = fmaf(h[k], w2[k * 2 * HID + c], acc2);
    ss[g * 2 * HID + c] = acc2;
}

// ---------------- K2: node pre-transform + zero degree counters ----------------
__global__ void node_pre_kernel(const float* __restrict__ x, const int* __restrict__ batch,
                                const float* __restrict__ ss,
                                float* __restrict__ x_t, int* __restrict__ cnt_int) {
    const int tid = blockIdx.x * blockDim.x + threadIdx.x;  // exactly N*32 threads
    const int n = tid >> 5, c = tid & 31;
    const int g = batch[n];
    const float scale = ss[g * 64 + c];
    const float shift = ss[g * 64 + 32 + c];
    const float v = x[tid];
    x_t[tid] = silu_f(fmaf(v, scale, v) + shift);
    if (c == 0) cnt_int[n] = 0;
}

// ---------------- K3: destination histogram ----------------
__global__ void hist_kernel(const int* __restrict__ ei, int* __restrict__ cnt_int) {
    const int e = blockIdx.x * blockDim.x + threadIdx.x;
    if (e >= NEDGE) return;
    atomicAdd(&cnt_int[ei[NEDGE + e]], 1);
}

// ---------------- K4a/b/c: exclusive scan of degrees ----------------
__global__ void scan1_kernel(const int* __restrict__ cnt_int, int* __restrict__ part,
                             int* __restrict__ blk) {
    __shared__ int s[SCAN_BLK];
    const int tid = threadIdx.x;
    const int i = blockIdx.x * SCAN_BLK + tid;
    const int v = (i < NNODE) ? cnt_int[i] : 0;
    s[tid] = v;
    __syncthreads();
    for (int off = 1; off < SCAN_BLK; off <<= 1) {
        int t = (tid >= off) ? s[tid - off] : 0;
        __syncthreads();
        s[tid] += t;
        __syncthreads();
    }
    part[i] = s[tid] - v;  // exclusive
    if (tid == SCAN_BLK - 1) blk[blockIdx.x] = s[tid];
}

__global__ void scan2_kernel(int* __restrict__ blk, int* __restrict__ blk_off) {
    __shared__ int s[128];
    const int tid = threadIdx.x;
    const int v = (tid < NBLK1) ? blk[tid] : 0;
    s[tid] = v;
    __syncthreads();
    for (int off = 1; off < 128; off <<= 1) {
        int t = (tid >= off) ? s[tid - off] : 0;
        __syncthreads();
        s[tid] += t;
        __syncthreads();
    }
    blk_off[tid] = s[tid] - v;
}

__global__ void scan3_kernel(const int* __restrict__ part, const int* __restrict__ blk_off,
                             const int* __restrict__ cnt_int,
                             int* __restrict__ offsets, int* __restrict__ cursor,
                             float* __restrict__ cnt_f) {
    const int i = blockIdx.x * blockDim.x + threadIdx.x;
    if (i >= NNODE) return;
    const int o = part[i] + blk_off[i >> 10];
    offsets[i] = o;
    cursor[i] = o;
    cnt_f[i] = (float)cnt_int[i];
}

// ---------------- K5: edge kernel (thread per edge, CSR scatter, NO f32 atomics) ----------------
__global__ __launch_bounds__(256) void edge_kernel(
    const int* __restrict__ ei, const float* __restrict__ x_t, const float* __restrict__ pos,
    const float* __restrict__ rbf_means, const float* __restrict__ rbf_betas,
    const float* __restrict__ w_dist,
    const float* __restrict__ msg_w1, const float* __restrict__ msg_b1,
    const float* __restrict__ msg_w2, const float* __restrict__ msg_b2,
    const float* __restrict__ gate_w, const float* __restrict__ gate_b,
    const float* __restrict__ coord_w1, const float* __restrict__ coord_b1,
    const float* __restrict__ coord_w2, const float* __restrict__ coord_b2,
    int* __restrict__ cursor, unsigned short* __restrict__ m_buf,
    float* __restrict__ pu_buf) {
    const int e = blockIdx.x * blockDim.x + threadIdx.x;
    if (e >= NEDGE) return;
    const int i = ei[e];
    const int j = ei[NEDGE + e];

    float xi[HID], xj[HID];
    {
        const float4* a4 = (const float4*)(x_t + i * HID);
        const float4* b4 = (const float4*)(x_t + j * HID);
#pragma unroll
        for (int q = 0; q < HID / 4; ++q) {
            float4 a = a4[q];
            xi[q * 4 + 0] = a.x; xi[q * 4 + 1] = a.y; xi[q * 4 + 2] = a.z; xi[q * 4 + 3] = a.w;
            float4 b = b4[q];
            xj[q * 4 + 0] = b.x; xj[q * 4 + 1] = b.y; xj[q * 4 + 2] = b.z; xj[q * 4 + 3] = b.w;
        }
    }

    // h = silu(cat(xi,xj) @ msg_w1 + b1)
    float h[HID];
#pragma unroll
    for (int c = 0; c < HID; ++c) h[c] = msg_b1[c];
#pragma unroll
    for (int k = 0; k < HID; ++k) {
        const float a = xi[k], b = xj[k];
#pragma unroll
        for (int c = 0; c < HID; ++c) {
            h[c] = fmaf(a, msg_w1[k * HID + c], h[c]);
            h[c] = fmaf(b, msg_w1[(HID + k) * HID + c], h[c]);
        }
    }
#pragma unroll
    for (int c = 0; c < HID; ++c) h[c] = silu_f(h[c]);

    // m = silu(h @ msg_w2 + b2)
    float m[HID];
#pragma unroll
    for (int c = 0; c < HID; ++c) m[c] = msg_b2[c];
#pragma unroll
    for (int k = 0; k < HID; ++k) {
        const float a = h[k];
#pragma unroll
        for (int c = 0; c < HID; ++c) m[c] = fmaf(a, msg_w2[k * HID + c], m[c]);
    }
#pragma unroll
    for (int c = 0; c < HID; ++c) m[c] = silu_f(m[c]);

    // gate = sigmoid(xj @ gate_w + gate_b); m *= gate
    {
        float ga[HID];
#pragma unroll
        for (int c = 0; c < HID; ++c) ga[c] = gate_b[c];
#pragma unroll
        for (int k = 0; k < HID; ++k) {
            const float a = xj[k];
#pragma unroll
            for (int c = 0; c < HID; ++c) ga[c] = fmaf(a, gate_w[k * HID + c], ga[c]);
        }
#pragma unroll
        for (int c = 0; c < HID; ++c) m[c] *= sigmoid_f(ga[c]);
    }

    // geometry
    const float p0 = pos[i * 3 + 0] - pos[j * 3 + 0];
    const float p1 = pos[i * 3 + 1] - pos[j * 3 + 1];
    const float p2 = pos[i * 3 + 2] - pos[j * 3 + 2];
    const float dist = sqrtf(p0 * p0 + p1 * p1 + p2 * p2);
    const float dcl = fminf(dist, 5.0f);
    const float cutoff = 0.5f * (__cosf(dcl * 0.6283185307179586f) + 1.0f);
    const float edm = __expf(-dist);
    {
        float rbf[HID];
#pragma unroll
        for (int c = 0; c < HID; ++c) {
            const float t = edm - rbf_means[c];
            rbf[c] = __expf(-rbf_betas[c] * t * t);
        }
        float de[HID];
#pragma unroll
        for (int c = 0; c < HID; ++c) de[c] = 0.0f;
#pragma unroll
        for (int k = 0; k < HID; ++k) {
            const float a = rbf[k];
#pragma unroll
            for (int c = 0; c < HID; ++c) de[c] = fmaf(a, w_dist[k * HID + c], de[c]);
        }
#pragma unroll
        for (int c = 0; c < HID; ++c) m[c] *= cutoff * de[c];
    }

    // s = silu(m @ coord_w1 + cb1) @ coord_w2 + cb2
    float s;
    {
        float sa[HID];
#pragma unroll
        for (int c = 0; c < HID; ++c) sa[c] = coord_b1[c];
#pragma unroll
        for (int k = 0; k < HID; ++k) {
            const float a = m[k];
#pragma unroll
            for (int c = 0; c < HID; ++c) sa[c] = fmaf(a, coord_w1[k * HID + c], sa[c]);
        }
        s = coord_b2[0];
#pragma unroll
        for (int c = 0; c < HID; ++c) s = fmaf(silu_f(sa[c]), coord_w2[c], s);
    }

    // CSR scatter: one int atomic, contiguous stores
    const int slot = atomicAdd(&cursor[j], 1);
    {
        unsigned int up[16];
#pragma unroll
        for (int q = 0; q < 16; ++q)
            up[q] = bf16r(m[2 * q]) | (bf16r(m[2 * q + 1]) << 16);
        uint4* dst = (uint4*)(m_buf + (size_t)slot * HID);
#pragma unroll
        for (int q = 0; q < 4; ++q)
            dst[q] = make_uint4(up[q * 4 + 0], up[q * 4 + 1], up[q * 4 + 2], up[q * 4 + 3]);
    }
    ((float4*)pu_buf)[slot] = make_float4(p0 * s, p1 * s, p2 * s, 0.0f);
}

// ---------------- K6: gather segment-sum (thread per node-channel) ----------------
__global__ void gather_kernel(const int* __restrict__ offsets, const int* __restrict__ cnt_int,
                              const unsigned short* __restrict__ m_buf,
                              const float* __restrict__ pu_buf,
                              float* __restrict__ m_i, float* __restrict__ sum_p) {
    const int tid = blockIdx.x * blockDim.x + threadIdx.x;  // N*32 threads
    const int n = tid >> 5, c = tid & 31;
    const int off = offsets[n];
    const int deg = cnt_int[n];
    float acc = 0.0f;
    for (int d = 0; d < deg; ++d)
        acc += bf16tof(m_buf[(size_t)(off + d) * HID + c]);
    m_i[tid] = acc;
    if (c < 3) {
        float a2 = 0.0f;
        for (int d = 0; d < deg; ++d)
            a2 += pu_buf[(size_t)(off + d) * 4 + c];
        sum_p[n * 3 + c] = a2;
    }
}

// ---------------- K7: node post (comb MLP + pos update) ----------------
__global__ void node_post_kernel(const float* __restrict__ x_t, const float* __restrict__ m_i,
                                 const float* __restrict__ pos, const float* __restrict__ sum_p,
                                 const float* __restrict__ cnt_f,
                                 const float* __restrict__ comb_w1, const float* __restrict__ comb_b1,
                                 const float* __restrict__ comb_w2, const float* __restrict__ comb_b2,
                                 float* __restrict__ out_x, float* __restrict__ out_pos) {
    const int n = blockIdx.x * blockDim.x + threadIdx.x;
    if (n >= NNODE) return;
    float xt[HID], mi[HID];
    {
        const float4* a4 = (const float4*)(x_t + n * HID);
        const float4* b4 = (const float4*)(m_i + n * HID);
#pragma unroll
        for (int q = 0; q < HID / 4; ++q) {
            float4 a = a4[q];
            xt[q * 4 + 0] = a.x; xt[q * 4 + 1] = a.y; xt[q * 4 + 2] = a.z; xt[q * 4 + 3] = a.w;
            float4 b = b4[q];
            mi[q * 4 + 0] = b.x; mi[q * 4 + 1] = b.y; mi[q * 4 + 2] = b.z; mi[q * 4 + 3] = b.w;
        }
    }
    float h[HID];
#pragma unroll
    for (int c = 0; c < HID; ++c) h[c] = comb_b1[c];
#pragma unroll
    for (int k = 0; k < HID; ++k) {
        const float a = xt[k], b = mi[k];
#pragma unroll
        for (int c = 0; c < HID; ++c) {
            h[c] = fmaf(a, comb_w1[k * HID + c], h[c]);
            h[c] = fmaf(b, comb_w1[(HID + k) * HID + c], h[c]);
        }
    }
#pragma unroll
    for (int c = 0; c < HID; ++c) h[c] = silu_f(h[c]);
    float c2[HID];
#pragma unroll
    for (int c = 0; c < HID; ++c) c2[c] = comb_b2[c];
#pragma unroll
    for (int k = 0; k < HID; ++k) {
        const float a = h[k];
#pragma unroll
        for (int c = 0; c < HID; ++c) c2[c] = fmaf(a, comb_w2[k * HID + c], c2[c]);
    }
#pragma unroll
    for (int c = 0; c < HID; ++c) out_x[n * HID + c] = silu_f(xt[c] + c2[c]);

    const float inv = 1.0f / fmaxf(cnt_f[n], 1.0f);
#pragma unroll
    for (int d = 0; d < 3; ++d) out_pos[n * 3 + d] = fmaf(sum_p[n * 3 + d], inv, pos[n * 3 + d]);
}

// ---------------- launch ----------------
extern "C" void kernel_launch(void* const* d_in, const int* in_sizes, int n_in,
                              void* d_out, int out_size, void* d_ws, size_t ws_size,
                              hipStream_t stream) {
    const float* x        = (const float*)d_in[0];
    const int*   ei       = (const int*)d_in[1];
    const float* pos      = (const float*)d_in[2];
    const float* timein   = (const float*)d_in[3];
    const int*   batch    = (const int*)d_in[4];
    const float* rbfm     = (const float*)d_in[5];
    const float* rbfb     = (const float*)d_in[6];
    const float* w_dist   = (const float*)d_in[7];
    const float* msg_w1   = (const float*)d_in[8];
    const float* msg_b1   = (const float*)d_in[9];
    const float* msg_w2   = (const float*)d_in[10];
    const float* msg_b2   = (const float*)d_in[11];
    const float* gate_w   = (const float*)d_in[12];
    const float* gate_b   = (const float*)d_in[13];
    const float* time_w1  = (const float*)d_in[14];
    const float* time_b1  = (const float*)d_in[15];
    const float* time_w2  = (const float*)d_in[16];
    const float* time_b2  = (const float*)d_in[17];
    const float* comb_w1  = (const float*)d_in[18];
    const float* comb_b1  = (const float*)d_in[19];
    const float* comb_w2  = (const float*)d_in[20];
    const float* comb_b2  = (const float*)d_in[21];
    const float* coord_w1 = (const float*)d_in[22];
    const float* coord_b1 = (const float*)d_in[23];
    const float* coord_w2 = (const float*)d_in[24];
    const float* coord_b2 = (const float*)d_in[25];

    // ---- workspace layout (all 16B aligned) ----
    char* w = (char*)d_ws;
    float* ss      = (float*)w;               w += (size_t)NGRAPH * 64 * 4;       // 131 KB
    float* x_t     = (float*)w;               w += (size_t)NNODE * HID * 4;       // 12.8 MB
    float* m_i     = (float*)w;               w += (size_t)NNODE * HID * 4;       // 12.8 MB
    float* sum_p   = (float*)w;               w += (size_t)NNODE * 3 * 4 + 4;     // 1.2 MB (+pad)
    float* cnt_f   = (float*)w;               w += (size_t)NNODE * 4;             // 0.4 MB
    int*   cnt_int = (int*)w;                 w += (size_t)NNODE * 4;
    int*   offsets = (int*)w;                 w += (size_t)NNODE * 4;
    int*   cursor  = (int*)w;                 w += (size_t)NNODE * 4;
    int*   part    = (int*)w;                 w += (size_t)NBLK1 * SCAN_BLK * 4;
    int*   blk     = (int*)w;                 w += 128 * 4;
    int*   blk_off = (int*)w;                 w += 128 * 4;
    w = (char*)(((size_t)w + 15) & ~(size_t)15);
    unsigned short* m_buf = (unsigned short*)w; w += (size_t)NEDGE * HID * 2;     // 51.2 MB
    float* pu_buf  = (float*)w;               /* NEDGE*4 floats = 12.8 MB */

    float* out_x   = (float*)d_out;           // N*32
    float* out_pos = out_x + NNODE * HID;     // N*3

    time_mlp_kernel<<<NGRAPH, 64, 0, stream>>>(timein, time_w1, time_b1, time_w2, time_b2, ss);
    node_pre_kernel<<<(NNODE * HID) / 256, 256, 0, stream>>>(x, batch, ss, x_t, cnt_int);
    hist_kernel<<<(NEDGE + 255) / 256, 256, 0, stream>>>(ei, cnt_int);
    scan1_kernel<<<NBLK1, SCAN_BLK, 0, stream>>>(cnt_int, part, blk);
    scan2_kernel<<<1, 128, 0, stream>>>(blk, blk_off);
    scan3_kernel<<<(NNODE + 255) / 256, 256, 0, stream>>>(part, blk_off, cnt_int,
                                                          offsets, cursor, cnt_f);
    edge_kernel<<<(NEDGE + 255) / 256, 256, 0, stream>>>(ei, x_t, pos, rbfm, rbfb, w_dist,
                                                         msg_w1, msg_b1, msg_w2, msg_b2,
                                                         gate_w, gate_b, coord_w1, coord_b1,
                                                         coord_w2, coord_b2,
                                                         cursor, m_buf, pu_buf);
    gather_kernel<<<(NNODE * HID) / 256, 256, 0, stream>>>(offsets, cnt_int, m_buf, pu_buf,
                                                           m_i, sum_p);
    node_post_kernel<<<(NNODE + 255) / 256, 256, 0, stream>>>(x_t, m_i, pos, sum_p, cnt_f,
                                                              comb_w1, comb_b1, comb_w2, comb_b2,
                                                              out_x, out_pos);
}

// Round 3
// 501.153 us; speedup vs baseline: 3.4999x; 1.2525x over previous
//
#include <hip/hip_runtime.h>
#include <math.h>

#define HID 32
#define TDIM 128
#define NNODE 100000
#define NEDGE 800000
#define NGRAPH 512
#define SCAN_BLK 1024
#define NBLK1 ((NNODE + SCAN_BLK - 1) / SCAN_BLK)   // 98
#define TPW 4   // edge tiles (of 16) per wave

typedef __attribute__((ext_vector_type(8))) short bf16x8;
typedef __attribute__((ext_vector_type(4))) float f32x4;

#define MFMA16(a, b, c) __builtin_amdgcn_mfma_f32_16x16x32_bf16(a, b, c, 0, 0, 0)

__device__ __forceinline__ float silu_f(float v) { return v / (1.0f + __expf(-v)); }
__device__ __forceinline__ float sigmoid_f(float v) { return 1.0f / (1.0f + __expf(-v)); }
__device__ __forceinline__ unsigned int bf16r(float f) {
    unsigned int u = __float_as_uint(f);
    return (u + 0x7FFFu + ((u >> 16) & 1u)) >> 16;   // RNE bf16
}
__device__ __forceinline__ float bf16tof(unsigned int h) {
    return __uint_as_float(h << 16);
}
__device__ __forceinline__ bf16x8 pack8(f32x4 a, f32x4 b) {
    bf16x8 r;
    r[0] = (short)bf16r(a[0]); r[1] = (short)bf16r(a[1]);
    r[2] = (short)bf16r(a[2]); r[3] = (short)bf16r(a[3]);
    r[4] = (short)bf16r(b[0]); r[5] = (short)bf16r(b[1]);
    r[6] = (short)bf16r(b[2]); r[7] = (short)bf16r(b[3]);
    return r;
}

// ---------------- K1: time MLP ----------------
__global__ void time_mlp_kernel(const float* __restrict__ timein,
                                const float* __restrict__ w1, const float* __restrict__ b1,
                                const float* __restrict__ w2, const float* __restrict__ b2,
                                float* __restrict__ ss) {
    __shared__ float t[TDIM];
    __shared__ float h[2 * HID];
    const int g = blockIdx.x;
    const int c = threadIdx.x;  // 0..63
    t[c]      = timein[g * TDIM + c];
    t[64 + c] = timein[g * TDIM + 64 + c];
    __syncthreads();
    float acc = b1[c];
#pragma unroll
    for (int k = 0; k < TDIM; ++k) acc = fmaf(t[k], w1[k * 2 * HID + c], acc);
    h[c] = silu_f(acc);
    __syncthreads();
    float acc2 = b2[c];
#pragma unroll
    for (int k = 0; k < 2 * HID; ++k) acc2 = fmaf(h[k], w2[k * 2 * HID + c], acc2);
    ss[g * 2 * HID + c] = acc2;
}

// ---------------- K2: node pre-transform (bf16 out) + zero degree counters ----------------
__global__ void node_pre_kernel(const float* __restrict__ x, const int* __restrict__ batch,
                                const float* __restrict__ ss,
                                unsigned short* __restrict__ x_bf, int* __restrict__ cnt_int) {
    const int tid = blockIdx.x * blockDim.x + threadIdx.x;  // N*32 threads
    const int n = tid >> 5, c = tid & 31;
    const int g = batch[n];
    const float scale = ss[g * 64 + c];
    const float shift = ss[g * 64 + 32 + c];
    const float v = x[tid];
    x_bf[tid] = (unsigned short)bf16r(silu_f(fmaf(v, scale, v) + shift));
    if (c == 0) cnt_int[n] = 0;
}

// ---------------- K2b: pre-swizzle weight B-fragments to bf16 ----------------
// B-frag mapping for mfma_f32_16x16x32_bf16: lane holds B[k=(lane>>4)*8+j][n=lane&15]
// frags: 0..3 msg_w1 (kt*2+nt), 4..5 msg_w2, 6..7 gate_w, 8..9 w_dist, 10..11 coord_w1
__global__ void prep_frags_kernel(const float* __restrict__ msg_w1, const float* __restrict__ msg_w2,
                                  const float* __restrict__ gate_w, const float* __restrict__ w_dist,
                                  const float* __restrict__ coord_w1,
                                  unsigned short* __restrict__ wf) {
    const int t = blockIdx.x * blockDim.x + threadIdx.x;
    if (t >= 12 * 512) return;
    const int frag = t >> 9;
    const int idx = t & 511;
    const int lane = idx >> 3, j = idx & 7;
    const int n16 = lane & 15, k = (lane >> 4) * 8 + j;
    const float* W; int kt, nt;
    if (frag < 4)       { W = msg_w1;   kt = frag >> 1; nt = frag & 1; }
    else if (frag < 6)  { W = msg_w2;   kt = 0; nt = frag - 4; }
    else if (frag < 8)  { W = gate_w;   kt = 0; nt = frag - 6; }
    else if (frag < 10) { W = w_dist;   kt = 0; nt = frag - 8; }
    else                { W = coord_w1; kt = 0; nt = frag - 10; }
    wf[t] = (unsigned short)bf16r(W[(kt * 32 + k) * 32 + nt * 16 + n16]);
}

// ---------------- K3: destination histogram ----------------
__global__ void hist_kernel(const int* __restrict__ ei, int* __restrict__ cnt_int) {
    const int e = blockIdx.x * blockDim.x + threadIdx.x;
    if (e >= NEDGE) return;
    atomicAdd(&cnt_int[ei[NEDGE + e]], 1);
}

// ---------------- K4: exclusive scan ----------------
__global__ void scan1_kernel(const int* __restrict__ cnt_int, int* __restrict__ part,
                             int* __restrict__ blk) {
    __shared__ int s[SCAN_BLK];
    const int tid = threadIdx.x;
    const int i = blockIdx.x * SCAN_BLK + tid;
    const int v = (i < NNODE) ? cnt_int[i] : 0;
    s[tid] = v;
    __syncthreads();
    for (int off = 1; off < SCAN_BLK; off <<= 1) {
        int t = (tid >= off) ? s[tid - off] : 0;
        __syncthreads();
        s[tid] += t;
        __syncthreads();
    }
    part[i] = s[tid] - v;
    if (tid == SCAN_BLK - 1) blk[blockIdx.x] = s[tid];
}

__global__ void scan2_kernel(int* __restrict__ blk, int* __restrict__ blk_off) {
    __shared__ int s[128];
    const int tid = threadIdx.x;
    const int v = (tid < NBLK1) ? blk[tid] : 0;
    s[tid] = v;
    __syncthreads();
    for (int off = 1; off < 128; off <<= 1) {
        int t = (tid >= off) ? s[tid - off] : 0;
        __syncthreads();
        s[tid] += t;
        __syncthreads();
    }
    blk_off[tid] = s[tid] - v;
}

__global__ void scan3_kernel(const int* __restrict__ part, const int* __restrict__ blk_off,
                             const int* __restrict__ cnt_int,
                             int* __restrict__ offsets, int* __restrict__ cursor,
                             float* __restrict__ cnt_f) {
    const int i = blockIdx.x * blockDim.x + threadIdx.x;
    if (i >= NNODE) return;
    const int o = part[i] + blk_off[i >> 10];
    offsets[i] = o;
    cursor[i] = o;
    cnt_f[i] = (float)cnt_int[i];
}

// ---------------- K5: MFMA edge kernel (wave = 16 edges per tile, TPW tiles) ----------------
__global__ __launch_bounds__(256) void edge_mfma_kernel(
    const int* __restrict__ ei, const unsigned short* __restrict__ x_bf,
    const float* __restrict__ pos,
    const float* __restrict__ rbf_means, const float* __restrict__ rbf_betas,
    const unsigned short* __restrict__ wf,
    const float* __restrict__ msg_b1, const float* __restrict__ msg_b2,
    const float* __restrict__ gate_b, const float* __restrict__ coord_b1,
    const float* __restrict__ coord_w2, const float* __restrict__ coord_b2,
    int* __restrict__ cursor, unsigned short* __restrict__ m_buf,
    float* __restrict__ pu_buf) {
    // per-wave private LDS (no __syncthreads needed: same-wave DS ops are in-order)
    __shared__ float lmat[4][16 * 36];   // 16x32 matrix, row stride 36 (16B-aligned, 2-way banks)
    __shared__ float lcut[4][16];
    __shared__ float lpd[4][16][4];
    __shared__ int   lslot[4][16];

    const int tid = threadIdx.x;
    const int wv = tid >> 6, lane = tid & 63;
    const int m16 = lane & 15, q = lane >> 4;
    float* Lm = lmat[wv];

    bf16x8 WF[12];
#pragma unroll
    for (int f = 0; f < 12; ++f) WF[f] = *(const bf16x8*)(wf + f * 512 + lane * 8);

    const float b1c0 = msg_b1[m16],   b1c1 = msg_b1[16 + m16];
    const float b2c0 = msg_b2[m16],   b2c1 = msg_b2[16 + m16];
    const float gbc0 = gate_b[m16],   gbc1 = gate_b[16 + m16];
    const float cb10 = coord_b1[m16], cb11 = coord_b1[16 + m16];
    const float cw20 = coord_w2[m16], cw21 = coord_w2[16 + m16];
    const float cb2  = coord_b2[0];
    const float4 rm0 = *(const float4*)(rbf_means + q * 8);
    const float4 rm1 = *(const float4*)(rbf_means + q * 8 + 4);
    const float4 rb0 = *(const float4*)(rbf_betas + q * 8);
    const float4 rb1 = *(const float4*)(rbf_betas + q * 8 + 4);

    const int wave_id = blockIdx.x * 4 + wv;
    const f32x4 z = {0.f, 0.f, 0.f, 0.f};

#pragma unroll 1
    for (int t = 0; t < TPW; ++t) {
        const int e = (wave_id * TPW + t) * 16 + m16;
        const int vi = ei[e], vj = ei[NEDGE + e];
        const bf16x8 xi = *(const bf16x8*)(x_bf + (size_t)vi * HID + q * 8);
        const bf16x8 xj = *(const bf16x8*)(x_bf + (size_t)vj * HID + q * 8);

        // geometry for edge m16 (duplicated across quads)
        const float p0 = pos[vi * 3 + 0] - pos[vj * 3 + 0];
        const float p1 = pos[vi * 3 + 1] - pos[vj * 3 + 1];
        const float p2 = pos[vi * 3 + 2] - pos[vj * 3 + 2];
        const float dist = sqrtf(p0 * p0 + p1 * p1 + p2 * p2);
        const float dcl = fminf(dist, 5.0f);
        const float cutoff = 0.5f * (__cosf(dcl * 0.6283185307179586f) + 1.0f);
        const float edm = __expf(-dist);
        if (q == 0) {
            lslot[wv][m16] = atomicAdd(&cursor[vj], 1);
            lcut[wv][m16] = cutoff;
            lpd[wv][m16][0] = p0; lpd[wv][m16][1] = p1; lpd[wv][m16][2] = p2;
        }

        // ---- L1: h = silu(cat(xi,xj) @ msg_w1 + b1) ----
        f32x4 h0 = MFMA16(xi, WF[0], z); h0 = MFMA16(xj, WF[2], h0);
        f32x4 h1 = MFMA16(xi, WF[1], z); h1 = MFMA16(xj, WF[3], h1);
#pragma unroll
        for (int r = 0; r < 4; ++r) {   // C-layout: row=q*4+r, col=nt*16+m16
            Lm[(q * 4 + r) * 36 + m16]      = silu_f(h0[r] + b1c0);
            Lm[(q * 4 + r) * 36 + 16 + m16] = silu_f(h1[r] + b1c1);
        }
        __builtin_amdgcn_s_waitcnt(0xC07F);  // lgkmcnt(0)
        // A-layout read: A[m=lane&15][k=q*8+j]
        f32x4 ha0 = *(const f32x4*)(Lm + m16 * 36 + q * 8);
        f32x4 ha1 = *(const f32x4*)(Lm + m16 * 36 + q * 8 + 4);
        const bf16x8 hf = pack8(ha0, ha1);

        // ---- L2, gate, dist_emb ----
        f32x4 am0 = MFMA16(hf, WF[4], z), am1 = MFMA16(hf, WF[5], z);
        f32x4 g0  = MFMA16(xj, WF[6], z), g1  = MFMA16(xj, WF[7], z);
        float rv[8];
        { float d;
          d = edm - rm0.x; rv[0] = __expf(-rb0.x * d * d);
          d = edm - rm0.y; rv[1] = __expf(-rb0.y * d * d);
          d = edm - rm0.z; rv[2] = __expf(-rb0.z * d * d);
          d = edm - rm0.w; rv[3] = __expf(-rb0.w * d * d);
          d = edm - rm1.x; rv[4] = __expf(-rb1.x * d * d);
          d = edm - rm1.y; rv[5] = __expf(-rb1.y * d * d);
          d = edm - rm1.z; rv[6] = __expf(-rb1.z * d * d);
          d = edm - rm1.w; rv[7] = __expf(-rb1.w * d * d); }
        bf16x8 rf;
#pragma unroll
        for (int k = 0; k < 8; ++k) rf[k] = (short)bf16r(rv[k]);
        f32x4 d0 = MFMA16(rf, WF[8], z), d1 = MFMA16(rf, WF[9], z);

        // ---- combine: m = silu(L2+b2) * sigmoid(gate) * cutoff * dist_emb ----
        __builtin_amdgcn_s_waitcnt(0xC07F);
#pragma unroll
        for (int r = 0; r < 4; ++r) {
            const float cu = lcut[wv][q * 4 + r];
            const float mv0 = silu_f(am0[r] + b2c0) * sigmoid_f(g0[r] + gbc0) * cu * d0[r];
            const float mv1 = silu_f(am1[r] + b2c1) * sigmoid_f(g1[r] + gbc1) * cu * d1[r];
            Lm[(q * 4 + r) * 36 + m16]      = mv0;
            Lm[(q * 4 + r) * 36 + 16 + m16] = mv1;
        }
        __builtin_amdgcn_s_waitcnt(0xC07F);
        f32x4 ma0 = *(const f32x4*)(Lm + m16 * 36 + q * 8);
        f32x4 ma1 = *(const f32x4*)(Lm + m16 * 36 + q * 8 + 4);
        const bf16x8 mf = pack8(ma0, ma1);

        // ---- coord layer + per-edge scalar s ----
        f32x4 c0 = MFMA16(mf, WF[10], z), c1 = MFMA16(mf, WF[11], z);
        float pp[4];
#pragma unroll
        for (int r = 0; r < 4; ++r)
            pp[r] = silu_f(c0[r] + cb10) * cw20 + silu_f(c1[r] + cb11) * cw21;
#pragma unroll
        for (int off = 1; off < 16; off <<= 1) {
#pragma unroll
            for (int r = 0; r < 4; ++r) pp[r] += __shfl_xor(pp[r], off);
        }

        // ---- m_buf store: lane -> edge em=lane>>2, chunk ch=lane&3 ----
        {
            const int em = lane >> 2, ch = lane & 3;
            f32x4 s0 = *(const f32x4*)(Lm + em * 36 + ch * 8);
            f32x4 s1 = *(const f32x4*)(Lm + em * 36 + ch * 8 + 4);
            const bf16x8 mb = pack8(s0, s1);
            const int sl = lslot[wv][em];
            *(bf16x8*)(m_buf + (size_t)sl * HID + ch * 8) = mb;
        }
        // ---- pu store: 16 lanes (m16<4), edge ep = q*4+m16, s = pp[m16]+cb2 ----
        if (m16 < 4) {
            const int ep = q * 4 + m16;
            const float sv = (m16 == 0 ? pp[0] : (m16 == 1 ? pp[1] : (m16 == 2 ? pp[2] : pp[3]))) + cb2;
            const int sl = lslot[wv][ep];
            ((float4*)pu_buf)[sl] = make_float4(lpd[wv][ep][0] * sv, lpd[wv][ep][1] * sv,
                                                lpd[wv][ep][2] * sv, 0.0f);
        }
    }
}

// ---------------- K6: gather segment-sum ----------------
__global__ void gather_kernel(const int* __restrict__ offsets, const int* __restrict__ cnt_int,
                              const unsigned short* __restrict__ m_buf,
                              const float* __restrict__ pu_buf,
                              float* __restrict__ m_i, float* __restrict__ sum_p) {
    const int tid = blockIdx.x * blockDim.x + threadIdx.x;  // N*32 threads
    const int n = tid >> 5, c = tid & 31;
    const int off = offsets[n];
    const int deg = cnt_int[n];
    float acc = 0.0f;
    for (int d = 0; d < deg; ++d)
        acc += bf16tof(m_buf[(size_t)(off + d) * HID + c]);
    m_i[tid] = acc;
    if (c < 3) {
        float a2 = 0.0f;
        for (int d = 0; d < deg; ++d)
            a2 += pu_buf[(size_t)(off + d) * 4 + c];
        sum_p[n * 3 + c] = a2;
    }
}

// ---------------- K7: node post ----------------
__global__ void node_post_kernel(const unsigned short* __restrict__ x_bf, const float* __restrict__ m_i,
                                 const float* __restrict__ pos, const float* __restrict__ sum_p,
                                 const float* __restrict__ cnt_f,
                                 const float* __restrict__ comb_w1, const float* __restrict__ comb_b1,
                                 const float* __restrict__ comb_w2, const float* __restrict__ comb_b2,
                                 float* __restrict__ out_x, float* __restrict__ out_pos) {
    const int n = blockIdx.x * blockDim.x + threadIdx.x;
    if (n >= NNODE) return;
    float xt[HID], mi[HID];
    {
        const uint4* xb = (const uint4*)(x_bf + (size_t)n * HID);
#pragma unroll
        for (int qq = 0; qq < 4; ++qq) {
            uint4 u = xb[qq];
            xt[qq * 8 + 0] = bf16tof(u.x & 0xffffu); xt[qq * 8 + 1] = bf16tof(u.x >> 16);
            xt[qq * 8 + 2] = bf16tof(u.y & 0xffffu); xt[qq * 8 + 3] = bf16tof(u.y >> 16);
            xt[qq * 8 + 4] = bf16tof(u.z & 0xffffu); xt[qq * 8 + 5] = bf16tof(u.z >> 16);
            xt[qq * 8 + 6] = bf16tof(u.w & 0xffffu); xt[qq * 8 + 7] = bf16tof(u.w >> 16);
        }
        const float4* b4 = (const float4*)(m_i + (size_t)n * HID);
#pragma unroll
        for (int qq = 0; qq < HID / 4; ++qq) {
            float4 b = b4[qq];
            mi[qq * 4 + 0] = b.x; mi[qq * 4 + 1] = b.y; mi[qq * 4 + 2] = b.z; mi[qq * 4 + 3] = b.w;
        }
    }
    float h[HID];
#pragma unroll
    for (int c = 0; c < HID; ++c) h[c] = comb_b1[c];
#pragma unroll
    for (int k = 0; k < HID; ++k) {
        const float a = xt[k], b = mi[k];
#pragma unroll
        for (int c = 0; c < HID; ++c) {
            h[c] = fmaf(a, comb_w1[k * HID + c], h[c]);
            h[c] = fmaf(b, comb_w1[(HID + k) * HID + c], h[c]);
        }
    }
#pragma unroll
    for (int c = 0; c < HID; ++c) h[c] = silu_f(h[c]);
    float c2[HID];
#pragma unroll
    for (int c = 0; c < HID; ++c) c2[c] = comb_b2[c];
#pragma unroll
    for (int k = 0; k < HID; ++k) {
        const float a = h[k];
#pragma unroll
        for (int c = 0; c < HID; ++c) c2[c] = fmaf(a, comb_w2[k * HID + c], c2[c]);
    }
#pragma unroll
    for (int c = 0; c < HID; ++c) out_x[n * HID + c] = silu_f(xt[c] + c2[c]);

    const float inv = 1.0f / fmaxf(cnt_f[n], 1.0f);
#pragma unroll
    for (int d = 0; d < 3; ++d) out_pos[n * 3 + d] = fmaf(sum_p[n * 3 + d], inv, pos[n * 3 + d]);
}

// ---------------- launch ----------------
extern "C" void kernel_launch(void* const* d_in, const int* in_sizes, int n_in,
                              void* d_out, int out_size, void* d_ws, size_t ws_size,
                              hipStream_t stream) {
    const float* x        = (const float*)d_in[0];
    const int*   ei       = (const int*)d_in[1];
    const float* pos      = (const float*)d_in[2];
    const float* timein   = (const float*)d_in[3];
    const int*   batch    = (const int*)d_in[4];
    const float* rbfm     = (const float*)d_in[5];
    const float* rbfb     = (const float*)d_in[6];
    const float* w_dist   = (const float*)d_in[7];
    const float* msg_w1   = (const float*)d_in[8];
    const float* msg_b1   = (const float*)d_in[9];
    const float* msg_w2   = (const float*)d_in[10];
    const float* msg_b2   = (const float*)d_in[11];
    const float* gate_w   = (const float*)d_in[12];
    const float* gate_b   = (const float*)d_in[13];
    const float* time_w1  = (const float*)d_in[14];
    const float* time_b1  = (const float*)d_in[15];
    const float* time_w2  = (const float*)d_in[16];
    const float* time_b2  = (const float*)d_in[17];
    const float* comb_w1  = (const float*)d_in[18];
    const float* comb_b1  = (const float*)d_in[19];
    const float* comb_w2  = (const float*)d_in[20];
    const float* comb_b2  = (const float*)d_in[21];
    const float* coord_w1 = (const float*)d_in[22];
    const float* coord_b1 = (const float*)d_in[23];
    const float* coord_w2 = (const float*)d_in[24];
    const float* coord_b2 = (const float*)d_in[25];

    char* w = (char*)d_ws;
    float* ss      = (float*)w;  w += (size_t)NGRAPH * 64 * 4;
    float* m_i     = (float*)w;  w += (size_t)NNODE * HID * 4;
    float* sum_p   = (float*)w;  w += (size_t)NNODE * 3 * 4 + 4;
    float* cnt_f   = (float*)w;  w += (size_t)NNODE * 4;
    int*   cnt_int = (int*)w;    w += (size_t)NNODE * 4;
    int*   offsets = (int*)w;    w += (size_t)NNODE * 4;
    int*   cursor  = (int*)w;    w += (size_t)NNODE * 4;
    int*   part    = (int*)w;    w += (size_t)NBLK1 * SCAN_BLK * 4;
    int*   blk     = (int*)w;    w += 128 * 4;
    int*   blk_off = (int*)w;    w += 128 * 4;
    w = (char*)(((size_t)w + 15) & ~(size_t)15);
    unsigned short* x_bf = (unsigned short*)w;  w += (size_t)NNODE * HID * 2;
    unsigned short* wf   = (unsigned short*)w;  w += (size_t)12 * 512 * 2;
    w = (char*)(((size_t)w + 15) & ~(size_t)15);
    unsigned short* m_buf = (unsigned short*)w; w += (size_t)NEDGE * HID * 2;
    float* pu_buf  = (float*)w;

    float* out_x   = (float*)d_out;
    float* out_pos = out_x + NNODE * HID;

    time_mlp_kernel<<<NGRAPH, 64, 0, stream>>>(timein, time_w1, time_b1, time_w2, time_b2, ss);
    node_pre_kernel<<<(NNODE * HID) / 256, 256, 0, stream>>>(x, batch, ss, x_bf, cnt_int);
    prep_frags_kernel<<<24, 256, 0, stream>>>(msg_w1, msg_w2, gate_w, w_dist, coord_w1, wf);
    hist_kernel<<<(NEDGE + 255) / 256, 256, 0, stream>>>(ei, cnt_int);
    scan1_kernel<<<NBLK1, SCAN_BLK, 0, stream>>>(cnt_int, part, blk);
    scan2_kernel<<<1, 128, 0, stream>>>(blk, blk_off);
    scan3_kernel<<<(NNODE + 255) / 256, 256, 0, stream>>>(part, blk_off, cnt_int,
                                                          offsets, cursor, cnt_f);
    edge_mfma_kernel<<<NEDGE / 256, 256, 0, stream>>>(ei, x_bf, pos, rbfm, rbfb, wf,
                                                      msg_b1, msg_b2, gate_b, coord_b1,
                                                      coord_w2, coord_b2,
                                                      cursor, m_buf, pu_buf);
    gather_kernel<<<(NNODE * HID) / 256, 256, 0, stream>>>(offsets, cnt_int, m_buf, pu_buf,
                                                           m_i, sum_p);
    node_post_kernel<<<(NNODE + 255) / 256, 256, 0, stream>>>(x_bf, m_i, pos, sum_p, cnt_f,
                                                              comb_w1, comb_b1, comb_w2, comb_b2,
                                                              out_x, out_pos);
}

// Round 4
// 279.630 us; speedup vs baseline: 6.2726x; 1.7922x over previous
//
#include <hip/hip_runtime.h>
#include <math.h>

#define HID 32
#define TDIM 128
#define NNODE 100000
#define NEDGE 800000
#define NGRAPH 512
#define SCAN_BLK 1024
#define NBLK1 ((NNODE + SCAN_BLK - 1) / SCAN_BLK)   // 98
#define TPW 4   // edge tiles (of 16) per wave
#define NFRAG 18

typedef __attribute__((ext_vector_type(8))) short bf16x8;
typedef __attribute__((ext_vector_type(4))) float f32x4;

#define MFMA16(a, b, c) __builtin_amdgcn_mfma_f32_16x16x32_bf16(a, b, c, 0, 0, 0)

__device__ __forceinline__ float silu_f(float v) { return v / (1.0f + __expf(-v)); }
__device__ __forceinline__ float sigmoid_f(float v) { return 1.0f / (1.0f + __expf(-v)); }
__device__ __forceinline__ unsigned int bf16r(float f) {
    unsigned int u = __float_as_uint(f);
    return (u + 0x7FFFu + ((u >> 16) & 1u)) >> 16;   // RNE bf16
}
__device__ __forceinline__ float bf16tof(unsigned int h) {
    return __uint_as_float(h << 16);
}
__device__ __forceinline__ bf16x8 pack8(f32x4 a, f32x4 b) {
    bf16x8 r;
    r[0] = (short)bf16r(a[0]); r[1] = (short)bf16r(a[1]);
    r[2] = (short)bf16r(a[2]); r[3] = (short)bf16r(a[3]);
    r[4] = (short)bf16r(b[0]); r[5] = (short)bf16r(b[1]);
    r[6] = (short)bf16r(b[2]); r[7] = (short)bf16r(b[3]);
    return r;
}

// ---------------- K1: time MLP ----------------
__global__ void time_mlp_kernel(const float* __restrict__ timein,
                                const float* __restrict__ w1, const float* __restrict__ b1,
                                const float* __restrict__ w2, const float* __restrict__ b2,
                                float* __restrict__ ss) {
    __shared__ float t[TDIM];
    __shared__ float h[2 * HID];
    const int g = blockIdx.x;
    const int c = threadIdx.x;  // 0..63
    t[c]      = timein[g * TDIM + c];
    t[64 + c] = timein[g * TDIM + 64 + c];
    __syncthreads();
    float acc = b1[c];
#pragma unroll
    for (int k = 0; k < TDIM; ++k) acc = fmaf(t[k], w1[k * 2 * HID + c], acc);
    h[c] = silu_f(acc);
    __syncthreads();
    float acc2 = b2[c];
#pragma unroll
    for (int k = 0; k < 2 * HID; ++k) acc2 = fmaf(h[k], w2[k * 2 * HID + c], acc2);
    ss[g * 2 * HID + c] = acc2;
}

// ---------------- K2: node pre-transform (bf16 out) + zero degree counters ----------------
__global__ void node_pre_kernel(const float* __restrict__ x, const int* __restrict__ batch,
                                const float* __restrict__ ss,
                                unsigned short* __restrict__ x_bf, int* __restrict__ cnt_int) {
    const int tid = blockIdx.x * blockDim.x + threadIdx.x;  // N*32 threads
    const int n = tid >> 5, c = tid & 31;
    const int g = batch[n];
    const float scale = ss[g * 64 + c];
    const float shift = ss[g * 64 + 32 + c];
    const float v = x[tid];
    x_bf[tid] = (unsigned short)bf16r(silu_f(fmaf(v, scale, v) + shift));
    if (c == 0) cnt_int[n] = 0;
}

// ---------------- K3: histogram + weight B-fragment prep ----------------
// B-frag mapping (mfma_f32_16x16x32_bf16): lane holds B[k=(lane>>4)*8+j][n=lane&15]
// frags: 0..3 msg_w1, 4..5 msg_w2, 6..7 gate_w, 8..9 w_dist, 10..11 coord_w1,
//        12..15 comb_w1, 16..17 comb_w2
__global__ void hist_prep_kernel(const int* __restrict__ ei, int* __restrict__ cnt_int,
                                 const float* __restrict__ msg_w1, const float* __restrict__ msg_w2,
                                 const float* __restrict__ gate_w, const float* __restrict__ w_dist,
                                 const float* __restrict__ coord_w1, const float* __restrict__ comb_w1,
                                 const float* __restrict__ comb_w2,
                                 unsigned short* __restrict__ wf) {
    const int t = blockIdx.x * blockDim.x + threadIdx.x;
    if (t < NFRAG * 512) {
        const int frag = t >> 9;
        const int idx = t & 511;
        const int lane = idx >> 3, j = idx & 7;
        const int n16 = lane & 15, k = (lane >> 4) * 8 + j;
        const float* W; int kt = 0, nt;
        if (frag < 4)       { W = msg_w1;   kt = frag >> 1;        nt = frag & 1; }
        else if (frag < 6)  { W = msg_w2;   nt = frag - 4; }
        else if (frag < 8)  { W = gate_w;   nt = frag - 6; }
        else if (frag < 10) { W = w_dist;   nt = frag - 8; }
        else if (frag < 12) { W = coord_w1; nt = frag - 10; }
        else if (frag < 16) { W = comb_w1;  kt = (frag - 12) >> 1; nt = (frag - 12) & 1; }
        else                { W = comb_w2;  nt = frag - 16; }
        wf[t] = (unsigned short)bf16r(W[(kt * 32 + k) * 32 + nt * 16 + n16]);
    }
    if (t < NEDGE) atomicAdd(&cnt_int[ei[NEDGE + t]], 1);
}

// ---------------- K4: exclusive scan ----------------
__global__ void scan1_kernel(const int* __restrict__ cnt_int, int* __restrict__ part,
                             int* __restrict__ blk) {
    __shared__ int s[SCAN_BLK];
    const int tid = threadIdx.x;
    const int i = blockIdx.x * SCAN_BLK + tid;
    const int v = (i < NNODE) ? cnt_int[i] : 0;
    s[tid] = v;
    __syncthreads();
    for (int off = 1; off < SCAN_BLK; off <<= 1) {
        int t = (tid >= off) ? s[tid - off] : 0;
        __syncthreads();
        s[tid] += t;
        __syncthreads();
    }
    part[i] = s[tid] - v;
    if (tid == SCAN_BLK - 1) blk[blockIdx.x] = s[tid];
}

__global__ void scan2_kernel(int* __restrict__ blk, int* __restrict__ blk_off) {
    __shared__ int s[128];
    const int tid = threadIdx.x;
    const int v = (tid < NBLK1) ? blk[tid] : 0;
    s[tid] = v;
    __syncthreads();
    for (int off = 1; off < 128; off <<= 1) {
        int t = (tid >= off) ? s[tid - off] : 0;
        __syncthreads();
        s[tid] += t;
        __syncthreads();
    }
    blk_off[tid] = s[tid] - v;
}

__global__ void scan3_kernel(const int* __restrict__ part, const int* __restrict__ blk_off,
                             int* __restrict__ offsets, int* __restrict__ cursor) {
    const int i = blockIdx.x * blockDim.x + threadIdx.x;
    if (i >= NNODE) return;
    const int o = part[i] + blk_off[i >> 10];
    offsets[i] = o;
    cursor[i] = o;
}

// ---------------- K5: MFMA edge kernel ----------------
__global__ __launch_bounds__(256) void edge_mfma_kernel(
    const int* __restrict__ ei, const unsigned short* __restrict__ x_bf,
    const float* __restrict__ pos,
    const float* __restrict__ rbf_means, const float* __restrict__ rbf_betas,
    const unsigned short* __restrict__ wf,
    const float* __restrict__ msg_b1, const float* __restrict__ msg_b2,
    const float* __restrict__ gate_b, const float* __restrict__ coord_b1,
    const float* __restrict__ coord_w2, const float* __restrict__ coord_b2,
    int* __restrict__ cursor, unsigned short* __restrict__ m_buf,
    float* __restrict__ pu_buf) {
    __shared__ float lmat[4][16 * 36];
    __shared__ float lcut[4][16];
    __shared__ float lpd[4][16][4];
    __shared__ int   lslot[4][16];

    const int tid = threadIdx.x;
    const int wv = tid >> 6, lane = tid & 63;
    const int m16 = lane & 15, q = lane >> 4;
    float* Lm = lmat[wv];

    bf16x8 WF[12];
#pragma unroll
    for (int f = 0; f < 12; ++f) WF[f] = *(const bf16x8*)(wf + f * 512 + lane * 8);

    const float b1c0 = msg_b1[m16],   b1c1 = msg_b1[16 + m16];
    const float b2c0 = msg_b2[m16],   b2c1 = msg_b2[16 + m16];
    const float gbc0 = gate_b[m16],   gbc1 = gate_b[16 + m16];
    const float cb10 = coord_b1[m16], cb11 = coord_b1[16 + m16];
    const float cw20 = coord_w2[m16], cw21 = coord_w2[16 + m16];
    const float cb2  = coord_b2[0];
    const float4 rm0 = *(const float4*)(rbf_means + q * 8);
    const float4 rm1 = *(const float4*)(rbf_means + q * 8 + 4);
    const float4 rb0 = *(const float4*)(rbf_betas + q * 8);
    const float4 rb1 = *(const float4*)(rbf_betas + q * 8 + 4);

    const int wave_id = blockIdx.x * 4 + wv;
    const f32x4 z = {0.f, 0.f, 0.f, 0.f};

#pragma unroll 1
    for (int t = 0; t < TPW; ++t) {
        const int e = (wave_id * TPW + t) * 16 + m16;
        const int vi = ei[e], vj = ei[NEDGE + e];
        const bf16x8 xi = *(const bf16x8*)(x_bf + (size_t)vi * HID + q * 8);
        const bf16x8 xj = *(const bf16x8*)(x_bf + (size_t)vj * HID + q * 8);

        const float p0 = pos[vi * 3 + 0] - pos[vj * 3 + 0];
        const float p1 = pos[vi * 3 + 1] - pos[vj * 3 + 1];
        const float p2 = pos[vi * 3 + 2] - pos[vj * 3 + 2];
        const float dist = sqrtf(p0 * p0 + p1 * p1 + p2 * p2);
        const float dcl = fminf(dist, 5.0f);
        const float cutoff = 0.5f * (__cosf(dcl * 0.6283185307179586f) + 1.0f);
        const float edm = __expf(-dist);
        if (q == 0) {
            lslot[wv][m16] = atomicAdd(&cursor[vj], 1);
            lcut[wv][m16] = cutoff;
            lpd[wv][m16][0] = p0; lpd[wv][m16][1] = p1; lpd[wv][m16][2] = p2;
        }

        // L1: h = silu(cat(xi,xj) @ msg_w1 + b1)
        f32x4 h0 = MFMA16(xi, WF[0], z); h0 = MFMA16(xj, WF[2], h0);
        f32x4 h1 = MFMA16(xi, WF[1], z); h1 = MFMA16(xj, WF[3], h1);
#pragma unroll
        for (int r = 0; r < 4; ++r) {
            Lm[(q * 4 + r) * 36 + m16]      = silu_f(h0[r] + b1c0);
            Lm[(q * 4 + r) * 36 + 16 + m16] = silu_f(h1[r] + b1c1);
        }
        __builtin_amdgcn_s_waitcnt(0xC07F);
        f32x4 ha0 = *(const f32x4*)(Lm + m16 * 36 + q * 8);
        f32x4 ha1 = *(const f32x4*)(Lm + m16 * 36 + q * 8 + 4);
        const bf16x8 hf = pack8(ha0, ha1);

        // L2, gate, dist_emb
        f32x4 am0 = MFMA16(hf, WF[4], z), am1 = MFMA16(hf, WF[5], z);
        f32x4 g0  = MFMA16(xj, WF[6], z), g1  = MFMA16(xj, WF[7], z);
        float rv[8];
        { float d;
          d = edm - rm0.x; rv[0] = __expf(-rb0.x * d * d);
          d = edm - rm0.y; rv[1] = __expf(-rb0.y * d * d);
          d = edm - rm0.z; rv[2] = __expf(-rb0.z * d * d);
          d = edm - rm0.w; rv[3] = __expf(-rb0.w * d * d);
          d = edm - rm1.x; rv[4] = __expf(-rb1.x * d * d);
          d = edm - rm1.y; rv[5] = __expf(-rb1.y * d * d);
          d = edm - rm1.z; rv[6] = __expf(-rb1.z * d * d);
          d = edm - rm1.w; rv[7] = __expf(-rb1.w * d * d); }
        bf16x8 rf;
#pragma unroll
        for (int k = 0; k < 8; ++k) rf[k] = (short)bf16r(rv[k]);
        f32x4 d0 = MFMA16(rf, WF[8], z), d1 = MFMA16(rf, WF[9], z);

        __builtin_amdgcn_s_waitcnt(0xC07F);
#pragma unroll
        for (int r = 0; r < 4; ++r) {
            const float cu = lcut[wv][q * 4 + r];
            const float mv0 = silu_f(am0[r] + b2c0) * sigmoid_f(g0[r] + gbc0) * cu * d0[r];
            const float mv1 = silu_f(am1[r] + b2c1) * sigmoid_f(g1[r] + gbc1) * cu * d1[r];
            Lm[(q * 4 + r) * 36 + m16]      = mv0;
            Lm[(q * 4 + r) * 36 + 16 + m16] = mv1;
        }
        __builtin_amdgcn_s_waitcnt(0xC07F);
        f32x4 ma0 = *(const f32x4*)(Lm + m16 * 36 + q * 8);
        f32x4 ma1 = *(const f32x4*)(Lm + m16 * 36 + q * 8 + 4);
        const bf16x8 mf = pack8(ma0, ma1);

        // coord layer + per-edge scalar s
        f32x4 c0 = MFMA16(mf, WF[10], z), c1 = MFMA16(mf, WF[11], z);
        float pp[4];
#pragma unroll
        for (int r = 0; r < 4; ++r)
            pp[r] = silu_f(c0[r] + cb10) * cw20 + silu_f(c1[r] + cb11) * cw21;
#pragma unroll
        for (int off = 1; off < 16; off <<= 1) {
#pragma unroll
            for (int r = 0; r < 4; ++r) pp[r] += __shfl_xor(pp[r], off);
        }

        {
            const int em = lane >> 2, ch = lane & 3;
            f32x4 s0 = *(const f32x4*)(Lm + em * 36 + ch * 8);
            f32x4 s1 = *(const f32x4*)(Lm + em * 36 + ch * 8 + 4);
            const bf16x8 mb = pack8(s0, s1);
            const int sl = lslot[wv][em];
            *(bf16x8*)(m_buf + (size_t)sl * HID + ch * 8) = mb;
        }
        if (m16 < 4) {
            const int ep = q * 4 + m16;
            const float sv = (m16 == 0 ? pp[0] : (m16 == 1 ? pp[1] : (m16 == 2 ? pp[2] : pp[3]))) + cb2;
            const int sl = lslot[wv][ep];
            ((float4*)pu_buf)[sl] = make_float4(lpd[wv][ep][0] * sv, lpd[wv][ep][1] * sv,
                                                lpd[wv][ep][2] * sv, 0.0f);
        }
    }
}

// ---------------- K6: fused gather + node post (MFMA, wave = 16 nodes) ----------------
__global__ __launch_bounds__(256) void node_post_mfma_kernel(
    const unsigned short* __restrict__ x_bf, const unsigned short* __restrict__ m_buf,
    const float* __restrict__ pu_buf,
    const int* __restrict__ offsets, const int* __restrict__ cnt_int,
    const float* __restrict__ pos, const unsigned short* __restrict__ wf,
    const float* __restrict__ comb_b1, const float* __restrict__ comb_b2,
    float* __restrict__ out_x, float* __restrict__ out_pos) {
    __shared__ float Lh[4][16 * 36];
    __shared__ float Lx[4][16 * 36];
    const int tid = threadIdx.x;
    const int wv = tid >> 6, lane = tid & 63;
    const int m16 = lane & 15, q = lane >> 4;
    const int wave_id = blockIdx.x * 4 + wv;
    if (wave_id * 16 >= NNODE) return;
    const int n = wave_id * 16 + m16;
    float* LH = Lh[wv];
    float* LX = Lx[wv];

    bf16x8 F[6];
#pragma unroll
    for (int f = 0; f < 6; ++f) F[f] = *(const bf16x8*)(wf + (12 + f) * 512 + lane * 8);
    const float b1c0 = comb_b1[m16], b1c1 = comb_b1[16 + m16];
    const float b2c0 = comb_b2[m16], b2c1 = comb_b2[16 + m16];

    // x A-fragment + decoded stash to LDS (for the residual epilogue)
    const bf16x8 xa = *(const bf16x8*)(x_bf + (size_t)n * HID + q * 8);
    {
        f32x4 xd0, xd1;
#pragma unroll
        for (int jj = 0; jj < 4; ++jj) {
            xd0[jj] = bf16tof((unsigned short)xa[jj]);
            xd1[jj] = bf16tof((unsigned short)xa[4 + jj]);
        }
        *(f32x4*)(LX + m16 * 36 + q * 8) = xd0;
        *(f32x4*)(LX + m16 * 36 + q * 8 + 4) = xd1;
    }

    // gather m_i for node n, channels q*8..q*8+7 (f32 accumulate over bucket)
    const int off = offsets[n];
    const int deg = cnt_int[n];
    float acc[8] = {0.f, 0.f, 0.f, 0.f, 0.f, 0.f, 0.f, 0.f};
    for (int d = 0; d < deg; ++d) {
        const bf16x8 mm = *(const bf16x8*)(m_buf + (size_t)(off + d) * HID + q * 8);
#pragma unroll
        for (int jj = 0; jj < 8; ++jj) acc[jj] += bf16tof((unsigned short)mm[jj]);
    }
    bf16x8 mi;
#pragma unroll
    for (int jj = 0; jj < 8; ++jj) mi[jj] = (short)bf16r(acc[jj]);

    // pos-update gather distributed over q, reduced via shuffle
    float a0 = 0.f, a1 = 0.f, a2 = 0.f;
    for (int d = q; d < deg; d += 4) {
        const float4 p = ((const float4*)pu_buf)[off + d];
        a0 += p.x; a1 += p.y; a2 += p.z;
    }
    a0 += __shfl_xor(a0, 16); a0 += __shfl_xor(a0, 32);
    a1 += __shfl_xor(a1, 16); a1 += __shfl_xor(a1, 32);
    a2 += __shfl_xor(a2, 16); a2 += __shfl_xor(a2, 32);

    // layer1: h = silu(cat(x, m_i) @ comb_w1 + b1)
    const f32x4 z = {0.f, 0.f, 0.f, 0.f};
    f32x4 h0 = MFMA16(xa, F[0], z); h0 = MFMA16(mi, F[2], h0);
    f32x4 h1 = MFMA16(xa, F[1], z); h1 = MFMA16(mi, F[3], h1);
#pragma unroll
    for (int r = 0; r < 4; ++r) {
        LH[(q * 4 + r) * 36 + m16]      = silu_f(h0[r] + b1c0);
        LH[(q * 4 + r) * 36 + 16 + m16] = silu_f(h1[r] + b1c1);
    }
    __builtin_amdgcn_s_waitcnt(0xC07F);
    f32x4 ha0 = *(const f32x4*)(LH + m16 * 36 + q * 8);
    f32x4 ha1 = *(const f32x4*)(LH + m16 * 36 + q * 8 + 4);
    const bf16x8 hf = pack8(ha0, ha1);

    // layer2 + residual silu epilogue (through LDS for coalesced store)
    f32x4 c0 = MFMA16(hf, F[4], z), c1 = MFMA16(hf, F[5], z);
#pragma unroll
    for (int r = 0; r < 4; ++r) {
        const float xv0 = LX[(q * 4 + r) * 36 + m16];
        const float xv1 = LX[(q * 4 + r) * 36 + 16 + m16];
        LH[(q * 4 + r) * 36 + m16]      = silu_f(xv0 + c0[r] + b2c0);
        LH[(q * 4 + r) * 36 + 16 + m16] = silu_f(xv1 + c1[r] + b2c1);
    }
    __builtin_amdgcn_s_waitcnt(0xC07F);
    {
        const int row = lane >> 2, col = (lane & 3) * 8;
        f32x4 o0 = *(const f32x4*)(LH + row * 36 + col);
        f32x4 o1 = *(const f32x4*)(LH + row * 36 + col + 4);
        float* dst = out_x + (size_t)(wave_id * 16 + row) * HID + col;
        *(f32x4*)dst = o0;
        *(f32x4*)(dst + 4) = o1;
    }
    if (q == 0) {
        const float inv = 1.0f / fmaxf((float)deg, 1.0f);
        out_pos[n * 3 + 0] = fmaf(a0, inv, pos[n * 3 + 0]);
        out_pos[n * 3 + 1] = fmaf(a1, inv, pos[n * 3 + 1]);
        out_pos[n * 3 + 2] = fmaf(a2, inv, pos[n * 3 + 2]);
    }
}

// ---------------- launch ----------------
extern "C" void kernel_launch(void* const* d_in, const int* in_sizes, int n_in,
                              void* d_out, int out_size, void* d_ws, size_t ws_size,
                              hipStream_t stream) {
    const float* x        = (const float*)d_in[0];
    const int*   ei       = (const int*)d_in[1];
    const float* pos      = (const float*)d_in[2];
    const float* timein   = (const float*)d_in[3];
    const int*   batch    = (const int*)d_in[4];
    const float* rbfm     = (const float*)d_in[5];
    const float* rbfb     = (const float*)d_in[6];
    const float* w_dist   = (const float*)d_in[7];
    const float* msg_w1   = (const float*)d_in[8];
    const float* msg_b1   = (const float*)d_in[9];
    const float* msg_w2   = (const float*)d_in[10];
    const float* msg_b2   = (const float*)d_in[11];
    const float* gate_w   = (const float*)d_in[12];
    const float* gate_b   = (const float*)d_in[13];
    const float* time_w1  = (const float*)d_in[14];
    const float* time_b1  = (const float*)d_in[15];
    const float* time_w2  = (const float*)d_in[16];
    const float* time_b2  = (const float*)d_in[17];
    const float* comb_w1  = (const float*)d_in[18];
    const float* comb_b1  = (const float*)d_in[19];
    const float* comb_w2  = (const float*)d_in[20];
    const float* comb_b2  = (const float*)d_in[21];
    const float* coord_w1 = (const float*)d_in[22];
    const float* coord_b1 = (const float*)d_in[23];
    const float* coord_w2 = (const float*)d_in[24];
    const float* coord_b2 = (const float*)d_in[25];

    char* w = (char*)d_ws;
    float* ss      = (float*)w;  w += (size_t)NGRAPH * 64 * 4;
    int*   cnt_int = (int*)w;    w += (size_t)NNODE * 4;
    int*   offsets = (int*)w;    w += (size_t)NNODE * 4;
    int*   cursor  = (int*)w;    w += (size_t)NNODE * 4;
    int*   part    = (int*)w;    w += (size_t)NBLK1 * SCAN_BLK * 4;
    int*   blk     = (int*)w;    w += 128 * 4;
    int*   blk_off = (int*)w;    w += 128 * 4;
    w = (char*)(((size_t)w + 15) & ~(size_t)15);
    unsigned short* x_bf = (unsigned short*)w;  w += (size_t)NNODE * HID * 2;
    unsigned short* wf   = (unsigned short*)w;  w += (size_t)NFRAG * 512 * 2;
    w = (char*)(((size_t)w + 15) & ~(size_t)15);
    unsigned short* m_buf = (unsigned short*)w; w += (size_t)NEDGE * HID * 2;
    float* pu_buf  = (float*)w;

    float* out_x   = (float*)d_out;
    float* out_pos = out_x + NNODE * HID;

    time_mlp_kernel<<<NGRAPH, 64, 0, stream>>>(timein, time_w1, time_b1, time_w2, time_b2, ss);
    node_pre_kernel<<<(NNODE * HID) / 256, 256, 0, stream>>>(x, batch, ss, x_bf, cnt_int);
    hist_prep_kernel<<<(NEDGE + 255) / 256, 256, 0, stream>>>(ei, cnt_int, msg_w1, msg_w2,
                                                              gate_w, w_dist, coord_w1,
                                                              comb_w1, comb_w2, wf);
    scan1_kernel<<<NBLK1, SCAN_BLK, 0, stream>>>(cnt_int, part, blk);
    scan2_kernel<<<1, 128, 0, stream>>>(blk, blk_off);
    scan3_kernel<<<(NNODE + 255) / 256, 256, 0, stream>>>(part, blk_off, offsets, cursor);
    edge_mfma_kernel<<<NEDGE / 256, 256, 0, stream>>>(ei, x_bf, pos, rbfm, rbfb, wf,
                                                      msg_b1, msg_b2, gate_b, coord_b1,
                                                      coord_w2, coord_b2,
                                                      cursor, m_buf, pu_buf);
    node_post_mfma_kernel<<<(NNODE / 16 + 3) / 4, 256, 0, stream>>>(x_bf, m_buf, pu_buf,
                                                                    offsets, cnt_int, pos, wf,
                                                                    comb_b1, comb_b2,
                                                                    out_x, out_pos);
}

// Round 5
// 258.621 us; speedup vs baseline: 6.7822x; 1.0812x over previous
//
#include <hip/hip_runtime.h>
#include <math.h>

#define HID 32
#define TDIM 128
#define NNODE 100000
#define NEDGE 800000
#define NGRAPH 512
#define SCAN_BLK 1024
#define NBLK1 ((NNODE + SCAN_BLK - 1) / SCAN_BLK)   // 98
#define TPW 4   // edge tiles (of 16) per wave
#define NFRAG 18

typedef __attribute__((ext_vector_type(8))) short bf16x8;
typedef __attribute__((ext_vector_type(4))) float f32x4;

#define MFMA16(a, b, c) __builtin_amdgcn_mfma_f32_16x16x32_bf16(a, b, c, 0, 0, 0)

// fast rational silu/sigmoid: v_rcp_f32 (~1 ulp) instead of exact-div sequence
__device__ __forceinline__ float silu_f(float v) {
    return v * __builtin_amdgcn_rcpf(1.0f + __expf(-v));
}
__device__ __forceinline__ float sigmoid_f(float v) {
    return __builtin_amdgcn_rcpf(1.0f + __expf(-v));
}
__device__ __forceinline__ unsigned int bf16r(float f) {
    unsigned int u = __float_as_uint(f);
    return (u + 0x7FFFu + ((u >> 16) & 1u)) >> 16;   // RNE (used in cold prep paths)
}
__device__ __forceinline__ float bf16tof(unsigned int h) {
    return __uint_as_float(h << 16);
}
// pack two f32 -> two bf16 (round-half-up) in 3 VALU ops via v_perm_b32
__device__ __forceinline__ unsigned int pk2(float a, float b) {
    unsigned int ia = __float_as_uint(a) + 0x8000u;
    unsigned int ib = __float_as_uint(b) + 0x8000u;
    return __builtin_amdgcn_perm(ib, ia, 0x07060302u);  // {ib[3:2], ia[3:2]}
}
__device__ __forceinline__ bf16x8 pack8(f32x4 a, f32x4 b) {
    union { unsigned int u[4]; bf16x8 v; } r;
    r.u[0] = pk2(a[0], a[1]);
    r.u[1] = pk2(a[2], a[3]);
    r.u[2] = pk2(b[0], b[1]);
    r.u[3] = pk2(b[2], b[3]);
    return r.v;
}

// ---------------- K1: time MLP ----------------
__global__ void time_mlp_kernel(const float* __restrict__ timein,
                                const float* __restrict__ w1, const float* __restrict__ b1,
                                const float* __restrict__ w2, const float* __restrict__ b2,
                                float* __restrict__ ss) {
    __shared__ float t[TDIM];
    __shared__ float h[2 * HID];
    const int g = blockIdx.x;
    const int c = threadIdx.x;  // 0..63
    t[c]      = timein[g * TDIM + c];
    t[64 + c] = timein[g * TDIM + 64 + c];
    __syncthreads();
    float acc = b1[c];
#pragma unroll
    for (int k = 0; k < TDIM; ++k) acc = fmaf(t[k], w1[k * 2 * HID + c], acc);
    h[c] = silu_f(acc);
    __syncthreads();
    float acc2 = b2[c];
#pragma unroll
    for (int k = 0; k < 2 * HID; ++k) acc2 = fmaf(h[k], w2[k * 2 * HID + c], acc2);
    ss[g * 2 * HID + c] = acc2;
}

// ---------------- K2: fused node-pre + histogram + weight-fragment prep ----------------
// grid = N*32/256 blocks; cnt_int must be zeroed (hipMemsetAsync) before this kernel.
__global__ void fused_pre_kernel(const float* __restrict__ x, const int* __restrict__ batch,
                                 const float* __restrict__ ss, const int* __restrict__ ei,
                                 unsigned short* __restrict__ x_bf, int* __restrict__ cnt_int,
                                 const float* __restrict__ msg_w1, const float* __restrict__ msg_w2,
                                 const float* __restrict__ gate_w, const float* __restrict__ w_dist,
                                 const float* __restrict__ coord_w1, const float* __restrict__ comb_w1,
                                 const float* __restrict__ comb_w2,
                                 unsigned short* __restrict__ wf) {
    const int t = blockIdx.x * blockDim.x + threadIdx.x;  // N*32 threads
    {
        const int n = t >> 5, c = t & 31;
        const int g = batch[n];
        const float scale = ss[g * 64 + c];
        const float shift = ss[g * 64 + 32 + c];
        const float v = x[t];
        x_bf[t] = (unsigned short)bf16r(silu_f(fmaf(v, scale, v) + shift));
    }
    if (t < NEDGE) atomicAdd(&cnt_int[ei[NEDGE + t]], 1);
    if (t < NFRAG * 512) {
        const int frag = t >> 9;
        const int idx = t & 511;
        const int lane = idx >> 3, j = idx & 7;
        const int n16 = lane & 15, k = (lane >> 4) * 8 + j;
        const float* W; int kt = 0, nt;
        if (frag < 4)       { W = msg_w1;   kt = frag >> 1;        nt = frag & 1; }
        else if (frag < 6)  { W = msg_w2;   nt = frag - 4; }
        else if (frag < 8)  { W = gate_w;   nt = frag - 6; }
        else if (frag < 10) { W = w_dist;   nt = frag - 8; }
        else if (frag < 12) { W = coord_w1; nt = frag - 10; }
        else if (frag < 16) { W = comb_w1;  kt = (frag - 12) >> 1; nt = (frag - 12) & 1; }
        else                { W = comb_w2;  nt = frag - 16; }
        wf[t] = (unsigned short)bf16r(W[(kt * 32 + k) * 32 + nt * 16 + n16]);
    }
}

// ---------------- K4: exclusive scan ----------------
__global__ void scan1_kernel(const int* __restrict__ cnt_int, int* __restrict__ part,
                             int* __restrict__ blk) {
    __shared__ int s[SCAN_BLK];
    const int tid = threadIdx.x;
    const int i = blockIdx.x * SCAN_BLK + tid;
    const int v = (i < NNODE) ? cnt_int[i] : 0;
    s[tid] = v;
    __syncthreads();
    for (int off = 1; off < SCAN_BLK; off <<= 1) {
        int t = (tid >= off) ? s[tid - off] : 0;
        __syncthreads();
        s[tid] += t;
        __syncthreads();
    }
    part[i] = s[tid] - v;
    if (tid == SCAN_BLK - 1) blk[blockIdx.x] = s[tid];
}

__global__ void scan2_kernel(int* __restrict__ blk, int* __restrict__ blk_off) {
    __shared__ int s[128];
    const int tid = threadIdx.x;
    const int v = (tid < NBLK1) ? blk[tid] : 0;
    s[tid] = v;
    __syncthreads();
    for (int off = 1; off < 128; off <<= 1) {
        int t = (tid >= off) ? s[tid - off] : 0;
        __syncthreads();
        s[tid] += t;
        __syncthreads();
    }
    blk_off[tid] = s[tid] - v;
}

__global__ void scan3_kernel(const int* __restrict__ part, const int* __restrict__ blk_off,
                             int* __restrict__ offsets, int* __restrict__ cursor) {
    const int i = blockIdx.x * blockDim.x + threadIdx.x;
    if (i >= NNODE) return;
    const int o = part[i] + blk_off[i >> 10];
    offsets[i] = o;
    cursor[i] = o;
}

// ---------------- K5: MFMA edge kernel ----------------
__global__ __launch_bounds__(256) void edge_mfma_kernel(
    const int* __restrict__ ei, const unsigned short* __restrict__ x_bf,
    const float* __restrict__ pos,
    const float* __restrict__ rbf_means, const float* __restrict__ rbf_betas,
    const unsigned short* __restrict__ wf,
    const float* __restrict__ msg_b1, const float* __restrict__ msg_b2,
    const float* __restrict__ gate_b, const float* __restrict__ coord_b1,
    const float* __restrict__ coord_w2, const float* __restrict__ coord_b2,
    int* __restrict__ cursor, unsigned short* __restrict__ m_buf,
    float* __restrict__ pu_buf) {
    __shared__ float lmat[4][16 * 36];
    __shared__ float lcut[4][16];
    __shared__ float lpd[4][16][4];
    __shared__ int   lslot[4][16];

    const int tid = threadIdx.x;
    const int wv = tid >> 6, lane = tid & 63;
    const int m16 = lane & 15, q = lane >> 4;
    float* Lm = lmat[wv];

    bf16x8 WF[12];
#pragma unroll
    for (int f = 0; f < 12; ++f) WF[f] = *(const bf16x8*)(wf + f * 512 + lane * 8);

    const float b1c0 = msg_b1[m16],   b1c1 = msg_b1[16 + m16];
    const float b2c0 = msg_b2[m16],   b2c1 = msg_b2[16 + m16];
    const float gbc0 = gate_b[m16],   gbc1 = gate_b[16 + m16];
    const float cb10 = coord_b1[m16], cb11 = coord_b1[16 + m16];
    const float cw20 = coord_w2[m16], cw21 = coord_w2[16 + m16];
    const float cb2  = coord_b2[0];
    const float4 rm0 = *(const float4*)(rbf_means + q * 8);
    const float4 rm1 = *(const float4*)(rbf_means + q * 8 + 4);
    const float4 rb0 = *(const float4*)(rbf_betas + q * 8);
    const float4 rb1 = *(const float4*)(rbf_betas + q * 8 + 4);

    const int wave_id = blockIdx.x * 4 + wv;
    const f32x4 z = {0.f, 0.f, 0.f, 0.f};

#pragma unroll 1
    for (int t = 0; t < TPW; ++t) {
        const int e = (wave_id * TPW + t) * 16 + m16;
        const int vi = ei[e], vj = ei[NEDGE + e];
        const bf16x8 xi = *(const bf16x8*)(x_bf + (size_t)vi * HID + q * 8);
        const bf16x8 xj = *(const bf16x8*)(x_bf + (size_t)vj * HID + q * 8);

        const float p0 = pos[vi * 3 + 0] - pos[vj * 3 + 0];
        const float p1 = pos[vi * 3 + 1] - pos[vj * 3 + 1];
        const float p2 = pos[vi * 3 + 2] - pos[vj * 3 + 2];
        const float dist = sqrtf(p0 * p0 + p1 * p1 + p2 * p2);
        const float dcl = fminf(dist, 5.0f);
        const float cutoff = 0.5f * (__cosf(dcl * 0.6283185307179586f) + 1.0f);
        const float edm = __expf(-dist);
        if (q == 0) {
            lslot[wv][m16] = atomicAdd(&cursor[vj], 1);
            lcut[wv][m16] = cutoff;
            lpd[wv][m16][0] = p0; lpd[wv][m16][1] = p1; lpd[wv][m16][2] = p2;
        }

        // L1: h = silu(cat(xi,xj) @ msg_w1 + b1)
        f32x4 h0 = MFMA16(xi, WF[0], z); h0 = MFMA16(xj, WF[2], h0);
        f32x4 h1 = MFMA16(xi, WF[1], z); h1 = MFMA16(xj, WF[3], h1);
#pragma unroll
        for (int r = 0; r < 4; ++r) {
            Lm[(q * 4 + r) * 36 + m16]      = silu_f(h0[r] + b1c0);
            Lm[(q * 4 + r) * 36 + 16 + m16] = silu_f(h1[r] + b1c1);
        }
        __builtin_amdgcn_s_waitcnt(0xC07F);
        f32x4 ha0 = *(const f32x4*)(Lm + m16 * 36 + q * 8);
        f32x4 ha1 = *(const f32x4*)(Lm + m16 * 36 + q * 8 + 4);
        const bf16x8 hf = pack8(ha0, ha1);

        // L2, gate, dist_emb
        f32x4 am0 = MFMA16(hf, WF[4], z), am1 = MFMA16(hf, WF[5], z);
        f32x4 g0  = MFMA16(xj, WF[6], z), g1  = MFMA16(xj, WF[7], z);
        float rv[8];
        { float d;
          d = edm - rm0.x; rv[0] = __expf(-rb0.x * d * d);
          d = edm - rm0.y; rv[1] = __expf(-rb0.y * d * d);
          d = edm - rm0.z; rv[2] = __expf(-rb0.z * d * d);
          d = edm - rm0.w; rv[3] = __expf(-rb0.w * d * d);
          d = edm - rm1.x; rv[4] = __expf(-rb1.x * d * d);
          d = edm - rm1.y; rv[5] = __expf(-rb1.y * d * d);
          d = edm - rm1.z; rv[6] = __expf(-rb1.z * d * d);
          d = edm - rm1.w; rv[7] = __expf(-rb1.w * d * d); }
        bf16x8 rf;
        { union { unsigned int u[4]; bf16x8 v; } rr;
          rr.u[0] = pk2(rv[0], rv[1]); rr.u[1] = pk2(rv[2], rv[3]);
          rr.u[2] = pk2(rv[4], rv[5]); rr.u[3] = pk2(rv[6], rv[7]);
          rf = rr.v; }
        f32x4 d0 = MFMA16(rf, WF[8], z), d1 = MFMA16(rf, WF[9], z);

        __builtin_amdgcn_s_waitcnt(0xC07F);
#pragma unroll
        for (int r = 0; r < 4; ++r) {
            const float cu = lcut[wv][q * 4 + r];
            const float mv0 = silu_f(am0[r] + b2c0) * sigmoid_f(g0[r] + gbc0) * cu * d0[r];
            const float mv1 = silu_f(am1[r] + b2c1) * sigmoid_f(g1[r] + gbc1) * cu * d1[r];
            Lm[(q * 4 + r) * 36 + m16]      = mv0;
            Lm[(q * 4 + r) * 36 + 16 + m16] = mv1;
        }
        __builtin_amdgcn_s_waitcnt(0xC07F);
        f32x4 ma0 = *(const f32x4*)(Lm + m16 * 36 + q * 8);
        f32x4 ma1 = *(const f32x4*)(Lm + m16 * 36 + q * 8 + 4);
        const bf16x8 mf = pack8(ma0, ma1);

        // coord layer + per-edge scalar s
        f32x4 c0 = MFMA16(mf, WF[10], z), c1 = MFMA16(mf, WF[11], z);
        float pp[4];
#pragma unroll
        for (int r = 0; r < 4; ++r)
            pp[r] = silu_f(c0[r] + cb10) * cw20 + silu_f(c1[r] + cb11) * cw21;
#pragma unroll
        for (int off = 1; off < 16; off <<= 1) {
#pragma unroll
            for (int r = 0; r < 4; ++r) pp[r] += __shfl_xor(pp[r], off);
        }

        {
            const int em = lane >> 2, ch = lane & 3;
            f32x4 s0 = *(const f32x4*)(Lm + em * 36 + ch * 8);
            f32x4 s1 = *(const f32x4*)(Lm + em * 36 + ch * 8 + 4);
            const bf16x8 mb = pack8(s0, s1);
            const int sl = lslot[wv][em];
            *(bf16x8*)(m_buf + (size_t)sl * HID + ch * 8) = mb;
        }
        if (m16 < 4) {
            const int ep = q * 4 + m16;
            const float sv = (m16 == 0 ? pp[0] : (m16 == 1 ? pp[1] : (m16 == 2 ? pp[2] : pp[3]))) + cb2;
            const int sl = lslot[wv][ep];
            ((float4*)pu_buf)[sl] = make_float4(lpd[wv][ep][0] * sv, lpd[wv][ep][1] * sv,
                                                lpd[wv][ep][2] * sv, 0.0f);
        }
    }
}

// ---------------- K6: fused gather + node post (MFMA, wave = 16 nodes) ----------------
__global__ __launch_bounds__(256) void node_post_mfma_kernel(
    const unsigned short* __restrict__ x_bf, const unsigned short* __restrict__ m_buf,
    const float* __restrict__ pu_buf,
    const int* __restrict__ offsets, const int* __restrict__ cnt_int,
    const float* __restrict__ pos, const unsigned short* __restrict__ wf,
    const float* __restrict__ comb_b1, const float* __restrict__ comb_b2,
    float* __restrict__ out_x, float* __restrict__ out_pos) {
    __shared__ float Lh[4][16 * 36];
    __shared__ float Lx[4][16 * 36];
    const int tid = threadIdx.x;
    const int wv = tid >> 6, lane = tid & 63;
    const int m16 = lane & 15, q = lane >> 4;
    const int wave_id = blockIdx.x * 4 + wv;
    if (wave_id * 16 >= NNODE) return;
    const int n = wave_id * 16 + m16;
    float* LH = Lh[wv];
    float* LX = Lx[wv];

    bf16x8 F[6];
#pragma unroll
    for (int f = 0; f < 6; ++f) F[f] = *(const bf16x8*)(wf + (12 + f) * 512 + lane * 8);
    const float b1c0 = comb_b1[m16], b1c1 = comb_b1[16 + m16];
    const float b2c0 = comb_b2[m16], b2c1 = comb_b2[16 + m16];

    const bf16x8 xa = *(const bf16x8*)(x_bf + (size_t)n * HID + q * 8);
    {
        f32x4 xd0, xd1;
#pragma unroll
        for (int jj = 0; jj < 4; ++jj) {
            xd0[jj] = bf16tof((unsigned short)xa[jj]);
            xd1[jj] = bf16tof((unsigned short)xa[4 + jj]);
        }
        *(f32x4*)(LX + m16 * 36 + q * 8) = xd0;
        *(f32x4*)(LX + m16 * 36 + q * 8 + 4) = xd1;
    }

    const int off = offsets[n];
    const int deg = cnt_int[n];
    float acc[8] = {0.f, 0.f, 0.f, 0.f, 0.f, 0.f, 0.f, 0.f};
    for (int d = 0; d < deg; ++d) {
        const bf16x8 mm = *(const bf16x8*)(m_buf + (size_t)(off + d) * HID + q * 8);
#pragma unroll
        for (int jj = 0; jj < 8; ++jj) acc[jj] += bf16tof((unsigned short)mm[jj]);
    }
    bf16x8 mi;
    { union { unsigned int u[4]; bf16x8 v; } rr;
      rr.u[0] = pk2(acc[0], acc[1]); rr.u[1] = pk2(acc[2], acc[3]);
      rr.u[2] = pk2(acc[4], acc[5]); rr.u[3] = pk2(acc[6], acc[7]);
      mi = rr.v; }

    float a0 = 0.f, a1 = 0.f, a2 = 0.f;
    for (int d = q; d < deg; d += 4) {
        const float4 p = ((const float4*)pu_buf)[off + d];
        a0 += p.x; a1 += p.y; a2 += p.z;
    }
    a0 += __shfl_xor(a0, 16); a0 += __shfl_xor(a0, 32);
    a1 += __shfl_xor(a1, 16); a1 += __shfl_xor(a1, 32);
    a2 += __shfl_xor(a2, 16); a2 += __shfl_xor(a2, 32);

    const f32x4 z = {0.f, 0.f, 0.f, 0.f};
    f32x4 h0 = MFMA16(xa, F[0], z); h0 = MFMA16(mi, F[2], h0);
    f32x4 h1 = MFMA16(xa, F[1], z); h1 = MFMA16(mi, F[3], h1);
#pragma unroll
    for (int r = 0; r < 4; ++r) {
        LH[(q * 4 + r) * 36 + m16]      = silu_f(h0[r] + b1c0);
        LH[(q * 4 + r) * 36 + 16 + m16] = silu_f(h1[r] + b1c1);
    }
    __builtin_amdgcn_s_waitcnt(0xC07F);
    f32x4 ha0 = *(const f32x4*)(LH + m16 * 36 + q * 8);
    f32x4 ha1 = *(const f32x4*)(LH + m16 * 36 + q * 8 + 4);
    const bf16x8 hf = pack8(ha0, ha1);

    f32x4 c0 = MFMA16(hf, F[4], z), c1 = MFMA16(hf, F[5], z);
#pragma unroll
    for (int r = 0; r < 4; ++r) {
        const float xv0 = LX[(q * 4 + r) * 36 + m16];
        const float xv1 = LX[(q * 4 + r) * 36 + 16 + m16];
        LH[(q * 4 + r) * 36 + m16]      = silu_f(xv0 + c0[r] + b2c0);
        LH[(q * 4 + r) * 36 + 16 + m16] = silu_f(xv1 + c1[r] + b2c1);
    }
    __builtin_amdgcn_s_waitcnt(0xC07F);
    {
        const int row = lane >> 2, col = (lane & 3) * 8;
        f32x4 o0 = *(const f32x4*)(LH + row * 36 + col);
        f32x4 o1 = *(const f32x4*)(LH + row * 36 + col + 4);
        float* dst = out_x + (size_t)(wave_id * 16 + row) * HID + col;
        *(f32x4*)dst = o0;
        *(f32x4*)(dst + 4) = o1;
    }
    if (q == 0) {
        const float inv = __builtin_amdgcn_rcpf(fmaxf((float)deg, 1.0f));
        out_pos[n * 3 + 0] = fmaf(a0, inv, pos[n * 3 + 0]);
        out_pos[n * 3 + 1] = fmaf(a1, inv, pos[n * 3 + 1]);
        out_pos[n * 3 + 2] = fmaf(a2, inv, pos[n * 3 + 2]);
    }
}

// ---------------- launch ----------------
extern "C" void kernel_launch(void* const* d_in, const int* in_sizes, int n_in,
                              void* d_out, int out_size, void* d_ws, size_t ws_size,
                              hipStream_t stream) {
    const float* x        = (const float*)d_in[0];
    const int*   ei       = (const int*)d_in[1];
    const float* pos      = (const float*)d_in[2];
    const float* timein   = (const float*)d_in[3];
    const int*   batch    = (const int*)d_in[4];
    const float* rbfm     = (const float*)d_in[5];
    const float* rbfb     = (const float*)d_in[6];
    const float* w_dist   = (const float*)d_in[7];
    const float* msg_w1   = (const float*)d_in[8];
    const float* msg_b1   = (const float*)d_in[9];
    const float* msg_w2   = (const float*)d_in[10];
    const float* msg_b2   = (const float*)d_in[11];
    const float* gate_w   = (const float*)d_in[12];
    const float* gate_b   = (const float*)d_in[13];
    const float* time_w1  = (const float*)d_in[14];
    const float* time_b1  = (const float*)d_in[15];
    const float* time_w2  = (const float*)d_in[16];
    const float* time_b2  = (const float*)d_in[17];
    const float* comb_w1  = (const float*)d_in[18];
    const float* comb_b1  = (const float*)d_in[19];
    const float* comb_w2  = (const float*)d_in[20];
    const float* comb_b2  = (const float*)d_in[21];
    const float* coord_w1 = (const float*)d_in[22];
    const float* coord_b1 = (const float*)d_in[23];
    const float* coord_w2 = (const float*)d_in[24];
    const float* coord_b2 = (const float*)d_in[25];

    char* w = (char*)d_ws;
    float* ss      = (float*)w;  w += (size_t)NGRAPH * 64 * 4;
    int*   cnt_int = (int*)w;    w += (size_t)NNODE * 4;
    int*   offsets = (int*)w;    w += (size_t)NNODE * 4;
    int*   cursor  = (int*)w;    w += (size_t)NNODE * 4;
    int*   part    = (int*)w;    w += (size_t)NBLK1 * SCAN_BLK * 4;
    int*   blk     = (int*)w;    w += 128 * 4;
    int*   blk_off = (int*)w;    w += 128 * 4;
    w = (char*)(((size_t)w + 15) & ~(size_t)15);
    unsigned short* x_bf = (unsigned short*)w;  w += (size_t)NNODE * HID * 2;
    unsigned short* wf   = (unsigned short*)w;  w += (size_t)NFRAG * 512 * 2;
    w = (char*)(((size_t)w + 15) & ~(size_t)15);
    unsigned short* m_buf = (unsigned short*)w; w += (size_t)NEDGE * HID * 2;
    float* pu_buf  = (float*)w;

    float* out_x   = (float*)d_out;
    float* out_pos = out_x + NNODE * HID;

    hipMemsetAsync(cnt_int, 0, (size_t)NNODE * 4, stream);
    time_mlp_kernel<<<NGRAPH, 64, 0, stream>>>(timein, time_w1, time_b1, time_w2, time_b2, ss);
    fused_pre_kernel<<<(NNODE * HID) / 256, 256, 0, stream>>>(x, batch, ss, ei, x_bf, cnt_int,
                                                              msg_w1, msg_w2, gate_w, w_dist,
                                                              coord_w1, comb_w1, comb_w2, wf);
    scan1_kernel<<<NBLK1, SCAN_BLK, 0, stream>>>(cnt_int, part, blk);
    scan2_kernel<<<1, 128, 0, stream>>>(blk, blk_off);
    scan3_kernel<<<(NNODE + 255) / 256, 256, 0, stream>>>(part, blk_off, offsets, cursor);
    edge_mfma_kernel<<<NEDGE / 256, 256, 0, stream>>>(ei, x_bf, pos, rbfm, rbfb, wf,
                                                      msg_b1, msg_b2, gate_b, coord_b1,
                                                      coord_w2, coord_b2,
                                                      cursor, m_buf, pu_buf);
    node_post_mfma_kernel<<<(NNODE / 16 + 3) / 4, 256, 0, stream>>>(x_bf, m_buf, pu_buf,
                                                                    offsets, cnt_int, pos, wf,
                                                                    comb_b1, comb_b2,
                                                                    out_x, out_pos);
}